// Round 7
// baseline (663.771 us; speedup 1.0000x reference)
//
#include <hip/hip_runtime.h>
#include <hip/hip_bf16.h>

typedef unsigned short u16;
typedef unsigned int u32;
typedef unsigned long long u64;
typedef float f32x4 __attribute__((ext_vector_type(4)));
typedef float f32x16 __attribute__((ext_vector_type(16)));
typedef u16 u16x4 __attribute__((ext_vector_type(4)));
typedef u16 u16x8 __attribute__((ext_vector_type(8)));
typedef short s16x8 __attribute__((ext_vector_type(8)));

// ---------- helpers ----------
__device__ __forceinline__ u16 f2b(float f) {
  return __builtin_bit_cast(u16, __float2bfloat16(f));
}
__device__ __forceinline__ float b2f(u16 u) {
  return __builtin_bit_cast(float, ((u32)u) << 16);
}
__device__ __forceinline__ f32x4 ldb4(const u16* __restrict__ p) {
  u16x4 v = *(const u16x4*)p;
  f32x4 r;
#pragma unroll
  for (int i = 0; i < 4; ++i) r[i] = b2f(v[i]);
  return r;
}
__device__ __forceinline__ f32x4 sigm4(f32x4 x) {
  f32x4 r;
#pragma unroll
  for (int i = 0; i < 4; ++i) r[i] = 1.0f / (1.0f + __expf(-x[i]));
  return r;
}
__device__ __forceinline__ f32x4 tanh4(f32x4 x) {
  f32x4 r;
#pragma unroll
  for (int i = 0; i < 4; ++i) {
    float xx = fminf(fmaxf(x[i], -15.0f), 15.0f);
    float e = __expf(2.0f * xx);
    r[i] = (e - 1.0f) / (e + 1.0f);
  }
  return r;
}

__device__ __forceinline__ void gload_lds16(const void* g, void* l) {
  typedef __attribute__((address_space(1))) const u32 gq_t;
  typedef __attribute__((address_space(3))) u32 lq_t;
  gq_t* gp = (gq_t*)(u64)(size_t)g;
  lq_t* lp = (lq_t*)(u32)(size_t)l;
  __builtin_amdgcn_global_load_lds(gp, lp, 16, 0, 0);
}

__device__ __forceinline__ f32x16 mfma32(u16x8 a, u16x8 b, f32x16 c) {
  return __builtin_amdgcn_mfma_f32_32x32x16_bf16(
      __builtin_bit_cast(s16x8, a), __builtin_bit_cast(s16x8, b), c, 0, 0, 0);
}

// ---------- kernel 1: cast x, h0 to bf16 ----------
__global__ __launch_bounds__(256) void cvt2_kernel(
    const f32x4* __restrict__ x, const f32x4* __restrict__ h,
    u16x4* __restrict__ xb, u16x4* __restrict__ hb, int n4) {
  for (int i = blockIdx.x * blockDim.x + threadIdx.x; i < n4;
       i += gridDim.x * blockDim.x) {
    f32x4 a = x[i], b = h[i];
    u16x4 ra, rb;
#pragma unroll
    for (int j = 0; j < 4; ++j) { ra[j] = f2b(a[j]); rb[j] = f2b(b[j]); }
    xb[i] = ra;
    hb[i] = rb;
  }
}

// ---------- kernel 2: pack + transpose weights to bf16 [N][K] ----------
__global__ __launch_bounds__(256) void packw_kernel(
    const float* __restrict__ W_ioux, const float* __restrict__ b_ioux,
    const float* __restrict__ W_iouh_r, const float* __restrict__ W_iouh_l,
    const float* __restrict__ W_fx, const float* __restrict__ b_fx,
    const float* __restrict__ W_fh0, const float* __restrict__ W_fh1,
    const float* __restrict__ W_fh2, const float* __restrict__ W_fh3,
    u16* __restrict__ WxT, u16* __restrict__ WhT, float* __restrict__ bcat) {
  const int t = blockIdx.x * 256 + threadIdx.x;
  const int NXW = 4096 * 128;
  float v[8];
  if (t < NXW) {
    const int n = t & 4095;
    const int k0 = (t >> 12) * 8;
    if (n < 3072) {
#pragma unroll
      for (int j = 0; j < 8; ++j) v[j] = W_ioux[(size_t)(k0 + j) * 3072 + n];
    } else {
#pragma unroll
      for (int j = 0; j < 8; ++j) v[j] = W_fx[(size_t)(k0 + j) * 1024 + (n - 3072)];
    }
    u16x8 o;
#pragma unroll
    for (int j = 0; j < 8; ++j) o[j] = f2b(v[j]);
    *(u16x8*)(WxT + (size_t)n * 1024 + k0) = o;
    if (k0 == 0) bcat[n] = (n < 3072) ? b_ioux[n] : b_fx[n - 3072];
  } else {
    const int u = t - NXW;
    const int m = u & 8191;
    const int k0 = (u >> 13) * 8;
    if (m < 3072) {
#pragma unroll
      for (int j = 0; j < 8; ++j) v[j] = W_iouh_r[(size_t)(k0 + j) * 3072 + m];
    } else if (m < 6144) {
#pragma unroll
      for (int j = 0; j < 8; ++j) v[j] = W_iouh_l[(size_t)(k0 + j) * 3072 + (m - 3072)];
    } else if (m < 7168) {
      const int c = m - 6144;
#pragma unroll
      for (int j = 0; j < 8; ++j)
        v[j] = W_fh0[(size_t)(k0 + j) * 1024 + c] + W_fh1[(size_t)(k0 + j) * 1024 + c];
    } else {
      const int c = m - 7168;
#pragma unroll
      for (int j = 0; j < 8; ++j)
        v[j] = W_fh2[(size_t)(k0 + j) * 1024 + c] + W_fh3[(size_t)(k0 + j) * 1024 + c];
    }
    u16x8 o;
#pragma unroll
    for (int j = 0; j < 8; ++j) o[j] = f2b(v[j]);
    *(u16x8*)(WhT + (size_t)m * 1024 + k0) = o;
  }
}

// ---------- kernel 3: 256x256 NT GEMM, 32x32x16 MFMA, frag-contiguous LDS --
// 512 threads = 8 waves (2M x 4N), wave tile 128x64.
// LDS 128KB: A 2buf x [8 frag][4 ks][1KB] @0/@32768, B same @65536/@98304.
// Every 1KB block is one wave-fragment: ds_read = base + lane*16 (linear,
// zero conflicts); gload_lds dest is wave-linear, per-lane GLOBAL source does
// the permutation (rule #21, clean direction - no XOR swizzle at all).
// R6's phase/barrier/vmcnt schedule kept verbatim (hazard audit unchanged).

#define BARRIER __builtin_amdgcn_s_barrier()
#define LGKM0 asm volatile("s_waitcnt lgkmcnt(0)")
#define VMCNT(n) asm volatile("s_waitcnt vmcnt(" #n ")")

__global__ __launch_bounds__(512, 2) void gemm_bt(
    const u16* __restrict__ A, const u16* __restrict__ Bt,
    u16* __restrict__ C, const float* __restrict__ bias, int N, int nk) {
  __shared__ u16 lds_u16[65536];  // 128 KB
  char* ldsb = (char*)lds_u16;
  const int tid = threadIdx.x;
  const int lane = tid & 63;
  const int wave = tid >> 6;
  const int wm = wave >> 2, wn = wave & 3;
  const int K = nk * 64;

  // XCD-aware block swizzle (nwg % 8 == 0 by construction)
  const int nbn = N >> 8;
  const int nwg = gridDim.x;
  const int bid = blockIdx.x;
  const int swz = (bid & 7) * (nwg >> 3) + (bid >> 3);
  const int bm = swz / nbn, bn = swz % nbn;

  // staging: wave stages one 1KB frag-block per chunk-op.
  // chunk c holds frags {2c, 2c+1}; frag f = 2c + (wave>>2), ks = wave&3;
  // lane -> row (lane&31) of the frag, k-sub (lane>>5)*8.
  const int srow = (wave >> 2) * 32 + (lane & 31);
  const int kofs = (wave & 3) * 16 + (lane >> 5) * 8;
  const u16* Ab = A + (size_t)(bm * 256 + srow) * K + kofs;
  const u16* Bb = Bt + (size_t)(bn * 256 + srow) * K + kofs;

#define SAg(PB, c, kt)                                          \
  gload_lds16(Ab + (size_t)(c) * 64 * K + (size_t)(kt) * 64,    \
              ldsb + (PB) + (c) * 8192 + tid * 16)
#define SBg(PB, c, kt)                                          \
  gload_lds16(Bb + (size_t)(c) * 64 * K + (size_t)(kt) * 64,    \
              ldsb + 65536 + (PB) + (c) * 8192 + tid * 16)

  // fragment read bases: A frag (ms,j,ks) at wm*8192 + ms*16384 + j*4096 +
  // ks*1024 + lane*16; B frag (ns,ks) at 65536 + wn*4096 + ns*16384 + ks*1024.
  const int aA = wm * 8192 + lane * 16;
  const int aB = 65536 + wn * 4096 + lane * 16;

#define LDA(AR, PB, MS)                                                    \
  _Pragma("unroll") for (int j = 0; j < 2; ++j) _Pragma("unroll")          \
      for (int ks = 0; ks < 4; ++ks) AR[j][ks] =                           \
          *(const u16x8*)(ldsb + aA + (PB) + (MS)*16384 + j * 4096 + ks * 1024)
#define LDB(BR, PB, NS)                                                    \
  _Pragma("unroll") for (int ks = 0; ks < 4; ++ks) BR[ks] =                \
      *(const u16x8*)(ldsb + aB + (PB) + (NS)*16384 + ks * 1024)
#define MFMAQ(MS, NS, AR, BR)                                              \
  _Pragma("unroll") for (int ks = 0; ks < 4; ++ks) _Pragma("unroll")       \
      for (int j = 0; j < 2; ++j) acc[MS][NS][j] =                         \
          mfma32(AR[j][ks], BR[ks], acc[MS][NS][j])

  u16x8 ar0[2][4], ar1[2][4], br0[4], br1[4];
  f32x16 acc[2][2][2] = {};

  // prologue: tile0 all 8 chunks -> buf0; tile1's A01,B23 -> buf1
  {
    const int s1 = (nk > 1) ? 1 : 0;
    SAg(0, 0, 0); SAg(0, 1, 0); SAg(0, 2, 0); SAg(0, 3, 0);
    SBg(0, 0, 0); SBg(0, 1, 0); SBg(0, 2, 0); SBg(0, 3, 0);
    SAg(32768, 0, s1); SAg(32768, 1, s1);
    SBg(32768, 2, s1); SBg(32768, 3, s1);
  }
  VMCNT(4);  // tile0 landed; tile1's 4 stay in flight
  BARRIER;

#define TILEBODY(PB, QB, Tcur)                                          \
  {                                                                     \
    const int s1 = ((Tcur) + 1 < nk) ? (Tcur) + 1 : nk - 1;             \
    const int s2 = ((Tcur) + 2 < nk) ? (Tcur) + 2 : nk - 1;             \
    /* P1 (m0,n0): read br0,ar0 from PB; stage QB A23 (tile T+1) */     \
    LDB(br0, PB, 0);                                                    \
    LDA(ar0, PB, 0);                                                    \
    SAg(QB, 2, s1); SAg(QB, 3, s1);                                     \
    BARRIER;                                                            \
    LGKM0;                                                              \
    __builtin_amdgcn_s_setprio(1);                                      \
    MFMAQ(0, 0, ar0, br0);                                              \
    __builtin_amdgcn_s_setprio(0);                                      \
    BARRIER;                                                            \
    /* P2 (m0,n1): read br1; stage QB B01 (tile T+1) */                 \
    LDB(br1, PB, 1);                                                    \
    SBg(QB, 0, s1); SBg(QB, 1, s1);                                     \
    BARRIER;                                                            \
    LGKM0;                                                              \
    __builtin_amdgcn_s_setprio(1);                                      \
    MFMAQ(0, 1, ar0, br1);                                              \
    __builtin_amdgcn_s_setprio(0);                                      \
    BARRIER;                                                            \
    /* P3 (m1,n1): read ar1; stage PB A01 (tile T+2) */                 \
    LDA(ar1, PB, 1);                                                    \
    SAg(PB, 0, s2); SAg(PB, 1, s2);                                     \
    BARRIER;                                                            \
    LGKM0;                                                              \
    __builtin_amdgcn_s_setprio(1);                                      \
    MFMAQ(1, 1, ar1, br1);                                              \
    __builtin_amdgcn_s_setprio(0);                                      \
    BARRIER;                                                            \
    /* P4 (m1,n0): reuse ar1,br0; stage PB B23 (tile T+2); vmcnt(4) */  \
    SBg(PB, 2, s2); SBg(PB, 3, s2);                                     \
    __builtin_amdgcn_s_setprio(1);                                      \
    MFMAQ(1, 0, ar1, br0);                                              \
    __builtin_amdgcn_s_setprio(0);                                      \
    VMCNT(4);                                                           \
    BARRIER;                                                            \
  }

  for (int T = 0; T < nk; T += 2) {
    TILEBODY(0, 32768, T);
    TILEBODY(32768, 0, T + 1);
  }
  VMCNT(0);

  // epilogue: C/D 32x32 layout: col = lane&31, row = (r&3)+8*(r>>2)+4*(lane>>5)
  const int l31 = lane & 31;
  const int rsub = 4 * (lane >> 5);
#pragma unroll
  for (int ns = 0; ns < 2; ++ns) {
    const int col = bn * 256 + ns * 128 + wn * 32 + l31;
    const float bv = bias ? bias[col] : 0.0f;
#pragma unroll
    for (int ms = 0; ms < 2; ++ms)
#pragma unroll
      for (int j = 0; j < 2; ++j) {
        const int row0 = bm * 256 + ms * 128 + wm * 64 + j * 32 + rsub;
        f32x16 v = acc[ms][ns][j];
#pragma unroll
        for (int r = 0; r < 16; ++r) {
          const int row = row0 + (r & 3) + 8 * (r >> 2);
          C[(size_t)row * N + col] = f2b(v[r] + bv);
        }
      }
  }
#undef SAg
#undef SBg
#undef LDA
#undef LDB
#undef MFMAQ
#undef TILEBODY
}

// ---------- kernel 4: fused scatter/gather + gates ----------
__global__ __launch_bounds__(256) void fused_epi(
    const u16* __restrict__ XO, const u16* __restrict__ HO,
    const float* __restrict__ h0, const float* __restrict__ c0,
    const int* __restrict__ idd, const int* __restrict__ idr,
    const int* __restrict__ idl, float* __restrict__ outh,
    float* __restrict__ outc, int b0) {
  __shared__ int listD[512], listR[512], listL[512];
  __shared__ int cnt[3];
  const int j = blockIdx.x;
  const int lb = blockIdx.y;
  const int b = b0 + lb;
  const int tid = threadIdx.x;
  const int lane = tid & 63;
  const int wave = tid >> 6;

  if (wave < 3) {
    const int* ids = (wave == 0 ? idd : (wave == 1 ? idr : idl)) + (size_t)b * 512;
    int* lst = (wave == 0 ? listD : (wave == 1 ? listR : listL));
    int base = 0;
#pragma unroll
    for (int c2 = 0; c2 < 8; ++c2) {
      int l = c2 * 64 + lane;
      int id = ids[l];
      u64 m = __ballot(id == j);
      if (id == j) {
        int pos = __popcll(m & ((1ull << lane) - 1ull));
        lst[base + pos] = l;
      }
      base += __popcll(m);
    }
    if (lane == 0) cnt[wave] = base;
  }
  __syncthreads();

  const int nD = cnt[0], nR = cnt[1], nL = cnt[2];
  const size_t grow = (size_t)b * 512 + j;
  const int k = tid * 4;

  if (!((nD > 0) && (j != 0))) {
    f32x4 hv = *(const f32x4*)(h0 + grow * 1024 + k);
    f32x4 cv = *(const f32x4*)(c0 + grow * 1024 + k);
    *(f32x4*)(outh + grow * 1024 + k) = hv;
    *(f32x4*)(outc + grow * 1024 + k) = cv;
    return;
  }

  const size_t lrow = (size_t)lb * 512 + j;
  const u16* xo = XO + lrow * 4096;
  f32x4 ai = ldb4(xo + k);
  f32x4 ao = ldb4(xo + 1024 + k);
  f32x4 au = ldb4(xo + 2048 + k);
  f32x4 fx = ldb4(xo + 3072 + k);

  for (int t = 0; t < nR; ++t) {
    const u16* hr = HO + ((size_t)lb * 512 + listR[t]) * 8192;
    ai += ldb4(hr + k);
    ao += ldb4(hr + 1024 + k);
    au += ldb4(hr + 2048 + k);
  }
  for (int t = 0; t < nL; ++t) {
    const u16* hl = HO + ((size_t)lb * 512 + listL[t]) * 8192;
    ai += ldb4(hl + 3072 + k);
    ao += ldb4(hl + 4096 + k);
    au += ldb4(hl + 5120 + k);
  }
  f32x4 gi = sigm4(ai), go = sigm4(ao), gu = tanh4(au);
  f32x4 c = gi * gu;
  for (int t = 0; t < nD; ++t) {
    int child = listD[t];
    int rr = idr[(size_t)b * 512 + child];
    int ll = idl[(size_t)b * 512 + child];
    f32x4 fpre = fx + ldb4(HO + ((size_t)lb * 512 + rr) * 8192 + 6144 + k) +
                 ldb4(HO + ((size_t)lb * 512 + ll) * 8192 + 7168 + k);
    f32x4 fg = sigm4(fpre);
    f32x4 cc = *(const f32x4*)(c0 + ((size_t)b * 512 + child) * 1024 + k);
    c += fg * cc;
  }
  f32x4 h = go * tanh4(c);
  *(f32x4*)(outh + grow * 1024 + k) = h;
  *(f32x4*)(outc + grow * 1024 + k) = c;
}

// ---------- host ----------
extern "C" void kernel_launch(void* const* d_in, const int* in_sizes, int n_in,
                              void* d_out, int out_size, void* d_ws,
                              size_t ws_size, hipStream_t stream) {
  const float* x = (const float*)d_in[0];
  const float* h0 = (const float*)d_in[1];
  const float* c0 = (const float*)d_in[2];
  const float* W_ioux = (const float*)d_in[3];
  const float* b_ioux = (const float*)d_in[4];
  const float* W_iouh_r = (const float*)d_in[5];
  const float* W_iouh_l = (const float*)d_in[6];
  const float* W_fx = (const float*)d_in[7];
  const float* b_fx = (const float*)d_in[8];
  const float* W_fh0 = (const float*)d_in[9];
  const float* W_fh1 = (const float*)d_in[10];
  const float* W_fh2 = (const float*)d_in[11];
  const float* W_fh3 = (const float*)d_in[12];
  const int* idd = (const int*)d_in[13];
  const int* idr = (const int*)d_in[14];
  const int* idl = (const int*)d_in[15];

  const size_t M = 16384;  // B*L
  char* p = (char*)d_ws;
  u16* Xb = (u16*)p;   p += M * 1024 * 2;
  u16* Hb = (u16*)p;   p += M * 1024 * 2;
  u16* WxT = (u16*)p;  p += (size_t)4096 * 1024 * 2;
  u16* WhT = (u16*)p;  p += (size_t)8192 * 1024 * 2;
  float* bcat = (float*)p; p += (size_t)4096 * 4;
  const size_t base_sz = (size_t)(p - (char*)d_ws);
  const size_t per_cb = (size_t)512 * 4096 * 2 + (size_t)512 * 8192 * 2;
  int CB = 32;
  while (CB > 1 && base_sz + (size_t)CB * per_cb > ws_size) CB >>= 1;
  u16* XO = (u16*)p;   p += (size_t)CB * 512 * 4096 * 2;
  u16* HO = (u16*)p;

  float* outh = (float*)d_out;
  float* outc = outh + M * 1024;

  cvt2_kernel<<<2048, 256, 0, stream>>>((const f32x4*)x, (const f32x4*)h0,
                                        (u16x4*)Xb, (u16x4*)Hb,
                                        (int)(M * 1024 / 4));
  packw_kernel<<<6144, 256, 0, stream>>>(W_ioux, b_ioux, W_iouh_r, W_iouh_l,
                                         W_fx, b_fx, W_fh0, W_fh1, W_fh2, W_fh3,
                                         WxT, WhT, bcat);

  const int nc = 32 / CB;
  for (int c = 0; c < nc; ++c) {
    const int mrows = CB * 512;
    const u16* Ax = Xb + (size_t)c * CB * 512 * 1024;
    const u16* Ah = Hb + (size_t)c * CB * 512 * 1024;
    gemm_bt<<<(mrows / 256) * (4096 / 256), 512, 0, stream>>>(Ax, WxT, XO, bcat,
                                                              4096, 1024 / 64);
    gemm_bt<<<(mrows / 256) * (8192 / 256), 512, 0, stream>>>(Ah, WhT, HO,
                                                              nullptr, 8192,
                                                              1024 / 64);
    fused_epi<<<dim3(512, CB), 256, 0, stream>>>(XO, HO, h0, c0, idd, idr, idl,
                                                 outh, outc, c * CB);
  }
}

// Round 8
// 579.004 us; speedup vs baseline: 1.1464x; 1.1464x over previous
//
#include <hip/hip_runtime.h>
#include <hip/hip_bf16.h>

typedef unsigned short u16;
typedef unsigned int u32;
typedef unsigned long long u64;
typedef float f32x4 __attribute__((ext_vector_type(4)));
typedef u16 u16x4 __attribute__((ext_vector_type(4)));
typedef u16 u16x8 __attribute__((ext_vector_type(8)));
typedef short s16x8 __attribute__((ext_vector_type(8)));

// ---------- helpers ----------
__device__ __forceinline__ u16 f2b(float f) {
  return __builtin_bit_cast(u16, __float2bfloat16(f));
}
__device__ __forceinline__ float b2f(u16 u) {
  return __builtin_bit_cast(float, ((u32)u) << 16);
}
__device__ __forceinline__ f32x4 ldb4(const u16* __restrict__ p) {
  u16x4 v = *(const u16x4*)p;
  f32x4 r;
#pragma unroll
  for (int i = 0; i < 4; ++i) r[i] = b2f(v[i]);
  return r;
}
__device__ __forceinline__ f32x4 sigm4(f32x4 x) {
  f32x4 r;
#pragma unroll
  for (int i = 0; i < 4; ++i) r[i] = 1.0f / (1.0f + __expf(-x[i]));
  return r;
}
__device__ __forceinline__ f32x4 tanh4(f32x4 x) {
  f32x4 r;
#pragma unroll
  for (int i = 0; i < 4; ++i) {
    float xx = fminf(fmaxf(x[i], -15.0f), 15.0f);
    float e = __expf(2.0f * xx);
    r[i] = (e - 1.0f) / (e + 1.0f);
  }
  return r;
}

__device__ __forceinline__ void gload_lds16(const void* g, void* l) {
  typedef __attribute__((address_space(1))) const u32 gq_t;
  typedef __attribute__((address_space(3))) u32 lq_t;
  gq_t* gp = (gq_t*)(u64)(size_t)g;
  lq_t* lp = (lq_t*)(u32)(size_t)l;
  __builtin_amdgcn_global_load_lds(gp, lp, 16, 0, 0);
}

// Builtin MFMA: compiler sees operand deps -> inserts its own counted lgkm
// waits and pipelines ds_reads under the MFMA stream.
__device__ __forceinline__ f32x4 mfma_b(u16x8 a, u16x8 b, f32x4 c) {
  return __builtin_amdgcn_mfma_f32_16x16x32_bf16(
      __builtin_bit_cast(s16x8, a), __builtin_bit_cast(s16x8, b), c, 0, 0, 0);
}

// ---------- kernel 1: cast x, h0 to bf16 ----------
__global__ __launch_bounds__(256) void cvt2_kernel(
    const f32x4* __restrict__ x, const f32x4* __restrict__ h,
    u16x4* __restrict__ xb, u16x4* __restrict__ hb, int n4) {
  for (int i = blockIdx.x * blockDim.x + threadIdx.x; i < n4;
       i += gridDim.x * blockDim.x) {
    f32x4 a = x[i], b = h[i];
    u16x4 ra, rb;
#pragma unroll
    for (int j = 0; j < 4; ++j) { ra[j] = f2b(a[j]); rb[j] = f2b(b[j]); }
    xb[i] = ra;
    hb[i] = rb;
  }
}

// ---------- kernel 2: pack + transpose weights to bf16 [N][K] ----------
__global__ __launch_bounds__(256) void packw_kernel(
    const float* __restrict__ W_ioux, const float* __restrict__ b_ioux,
    const float* __restrict__ W_iouh_r, const float* __restrict__ W_iouh_l,
    const float* __restrict__ W_fx, const float* __restrict__ b_fx,
    const float* __restrict__ W_fh0, const float* __restrict__ W_fh1,
    const float* __restrict__ W_fh2, const float* __restrict__ W_fh3,
    u16* __restrict__ WxT, u16* __restrict__ WhT, float* __restrict__ bcat) {
  const int t = blockIdx.x * 256 + threadIdx.x;
  const int NXW = 4096 * 128;
  float v[8];
  if (t < NXW) {
    const int n = t & 4095;
    const int k0 = (t >> 12) * 8;
    if (n < 3072) {
#pragma unroll
      for (int j = 0; j < 8; ++j) v[j] = W_ioux[(size_t)(k0 + j) * 3072 + n];
    } else {
#pragma unroll
      for (int j = 0; j < 8; ++j) v[j] = W_fx[(size_t)(k0 + j) * 1024 + (n - 3072)];
    }
    u16x8 o;
#pragma unroll
    for (int j = 0; j < 8; ++j) o[j] = f2b(v[j]);
    *(u16x8*)(WxT + (size_t)n * 1024 + k0) = o;
    if (k0 == 0) bcat[n] = (n < 3072) ? b_ioux[n] : b_fx[n - 3072];
  } else {
    const int u = t - NXW;
    const int m = u & 8191;
    const int k0 = (u >> 13) * 8;
    if (m < 3072) {
#pragma unroll
      for (int j = 0; j < 8; ++j) v[j] = W_iouh_r[(size_t)(k0 + j) * 3072 + m];
    } else if (m < 6144) {
#pragma unroll
      for (int j = 0; j < 8; ++j) v[j] = W_iouh_l[(size_t)(k0 + j) * 3072 + (m - 3072)];
    } else if (m < 7168) {
      const int c = m - 6144;
#pragma unroll
      for (int j = 0; j < 8; ++j)
        v[j] = W_fh0[(size_t)(k0 + j) * 1024 + c] + W_fh1[(size_t)(k0 + j) * 1024 + c];
    } else {
      const int c = m - 7168;
#pragma unroll
      for (int j = 0; j < 8; ++j)
        v[j] = W_fh2[(size_t)(k0 + j) * 1024 + c] + W_fh3[(size_t)(k0 + j) * 1024 + c];
    }
    u16x8 o;
#pragma unroll
    for (int j = 0; j < 8; ++j) o[j] = f2b(v[j]);
    *(u16x8*)(WhT + (size_t)m * 1024 + k0) = o;
  }
}

// ---------- kernel 3: 256x256 4-phase NT GEMM, single-barrier phases --------
// 512 threads = 8 waves (2M x 4N), wave tile 128x64. LDS 128KB XOR-swizzled.
// Per phase: {ds_read frags, stage 2 gload_lds, lgkmcnt(0), setprio, 16 MFMA,
// setprio, s_barrier}. ONE counted vmcnt(4) per K-tile (P4, before barrier).
// Hazard audit (1 barrier/phase): every region has >=2 barriers between its
// read-certification (LGKM0 < phase barrier) and the stage-issue overwriting
// it; consumed-tile certification = prev tile's vmcnt(4) + tile-end barrier.

#define BARRIER __builtin_amdgcn_s_barrier()
#define LGKM0 asm volatile("s_waitcnt lgkmcnt(0)")
#define VMCNT(n) asm volatile("s_waitcnt vmcnt(" #n ")")

__global__ __launch_bounds__(512, 2) void gemm_bt(
    const u16* __restrict__ A, const u16* __restrict__ Bt,
    u16* __restrict__ C, const float* __restrict__ bias, int N, int nk) {
  __shared__ u16 lds_u16[65536];  // 128 KB: A 2x32KB @0, B 2x32KB @65536
  char* ldsb = (char*)lds_u16;
  const int tid = threadIdx.x;
  const int lane = tid & 63;
  const int wave = tid >> 6;
  const int wm = wave >> 2, wn = wave & 3;
  const int K = nk * 64;

  // XCD-aware block swizzle (nwg % 8 == 0 by construction)
  const int nbn = N >> 8;
  const int nwg = gridDim.x;
  const int bid = blockIdx.x;
  const int swz = (bid & 7) * (nwg >> 3) + (bid >> 3);
  const int bm = swz / nbn, bn = swz % nbn;

  // staging source: inverse-XOR-swizzled so swizzled ds_reads see linear data
  const int srow = tid >> 3;
  const int ssw = (((tid & 7) * 16) ^ ((srow & 7) << 4)) >> 1;
  const u16* Ab = A + (size_t)(bm * 256 + srow) * K + ssw;
  const u16* Bb = Bt + (size_t)(bn * 256 + srow) * K + ssw;

#define SAg(PB, c, kt)                                          \
  gload_lds16(Ab + (size_t)(c) * 64 * K + (size_t)(kt) * 64,    \
              ldsb + (PB) + (c) * 8192 + tid * 16)
#define SBg(PB, c, kt)                                          \
  gload_lds16(Bb + (size_t)(c) * 64 * K + (size_t)(kt) * 64,    \
              ldsb + 65536 + (PB) + (c) * 8192 + tid * 16)

  // fragment read offsets (XOR swizzle depends only on lane)
  const int lb15 = lane & 15;
  const int lh16 = (lane >> 4) * 16;
  const int sw = (lane & 7) << 4;
  int a_off[2], b_off[2];
  a_off[0] = (wm * 64 + lb15) * 128 + (lh16 ^ sw);
  a_off[1] = (wm * 64 + lb15) * 128 + ((64 + lh16) ^ sw);
  b_off[0] = 65536 + (wn * 32 + lb15) * 128 + (lh16 ^ sw);
  b_off[1] = 65536 + (wn * 32 + lb15) * 128 + ((64 + lh16) ^ sw);

#define LDA(AR, PB, MS)                                                    \
  _Pragma("unroll") for (int fm = 0; fm < 4; ++fm) _Pragma("unroll")       \
      for (int kk = 0; kk < 2; ++kk) AR[fm][kk] =                          \
          *(const u16x8*)(ldsb + (PB) + a_off[kk] + (MS)*16384 + fm * 2048)
#define LDB(BR, PB, NS)                                                    \
  _Pragma("unroll") for (int fn = 0; fn < 2; ++fn) _Pragma("unroll")       \
      for (int kk = 0; kk < 2; ++kk) BR[fn][kk] =                          \
          *(const u16x8*)(ldsb + (PB) + b_off[kk] + (NS)*16384 + fn * 2048)
#define MFMAQ(MS, NS, AR, BR)                                              \
  _Pragma("unroll") for (int kk = 0; kk < 2; ++kk) _Pragma("unroll")       \
      for (int fm = 0; fm < 4; ++fm) _Pragma("unroll")                     \
      for (int fn = 0; fn < 2; ++fn) acc[MS][fm][NS][fn] =                 \
          mfma_b(AR[fm][kk], BR[fn][kk], acc[MS][fm][NS][fn])

  u16x8 ar0[4][2], ar1[4][2], br0[2][2], br1[2][2];
  f32x4 acc[2][4][2][2] = {};

  // prologue: tile0 all 8 chunks -> buf0; tile1's A01,B23 -> buf1
  {
    const int s1 = (nk > 1) ? 1 : 0;
    SAg(0, 0, 0); SAg(0, 1, 0); SAg(0, 2, 0); SAg(0, 3, 0);
    SBg(0, 0, 0); SBg(0, 1, 0); SBg(0, 2, 0); SBg(0, 3, 0);
    SAg(32768, 0, s1); SAg(32768, 1, s1);
    SBg(32768, 2, s1); SBg(32768, 3, s1);
  }
  VMCNT(4);  // tile0 landed; tile1's 4 stay in flight
  BARRIER;

  // TILEBODY: literal buffer byte-offset PB (0 or 32768); QB = other buffer.
  // ONE barrier per phase (at phase end).
#define TILEBODY(PB, QB, Tcur)                                          \
  {                                                                     \
    const int s1 = ((Tcur) + 1 < nk) ? (Tcur) + 1 : nk - 1;             \
    const int s2 = ((Tcur) + 2 < nk) ? (Tcur) + 2 : nk - 1;             \
    /* P1 (m0,n0): read br0,ar0 from PB; stage QB A23 (tile T+1) */     \
    LDB(br0, PB, 0);                                                    \
    LDA(ar0, PB, 0);                                                    \
    SAg(QB, 2, s1); SAg(QB, 3, s1);                                     \
    LGKM0;                                                              \
    __builtin_amdgcn_s_setprio(1);                                      \
    MFMAQ(0, 0, ar0, br0);                                              \
    __builtin_amdgcn_s_setprio(0);                                      \
    BARRIER;                                                            \
    /* P2 (m0,n1): read br1; stage QB B01 (tile T+1) */                 \
    LDB(br1, PB, 1);                                                    \
    SBg(QB, 0, s1); SBg(QB, 1, s1);                                     \
    LGKM0;                                                              \
    __builtin_amdgcn_s_setprio(1);                                      \
    MFMAQ(0, 1, ar0, br1);                                              \
    __builtin_amdgcn_s_setprio(0);                                      \
    BARRIER;                                                            \
    /* P3 (m1,n1): read ar1; stage PB A01 (tile T+2) */                 \
    LDA(ar1, PB, 1);                                                    \
    SAg(PB, 0, s2); SAg(PB, 1, s2);                                     \
    LGKM0;                                                              \
    __builtin_amdgcn_s_setprio(1);                                      \
    MFMAQ(1, 1, ar1, br1);                                              \
    __builtin_amdgcn_s_setprio(0);                                      \
    BARRIER;                                                            \
    /* P4 (m1,n0): reuse ar1,br0; stage PB B23 (tile T+2); vmcnt(4) */  \
    SBg(PB, 2, s2); SBg(PB, 3, s2);                                     \
    __builtin_amdgcn_s_setprio(1);                                      \
    MFMAQ(1, 0, ar1, br0);                                              \
    __builtin_amdgcn_s_setprio(0);                                      \
    VMCNT(4);                                                           \
    BARRIER;                                                            \
  }

  for (int T = 0; T < nk; T += 2) {
    TILEBODY(0, 32768, T);
    TILEBODY(32768, 0, T + 1);
  }
  VMCNT(0);

  // epilogue: wave rows {wm*64.., 128+wm*64..}, cols {wn*32.., 128+wn*32..}
#pragma unroll
  for (int ms = 0; ms < 2; ++ms)
#pragma unroll
    for (int fm = 0; fm < 4; ++fm) {
      const int row0 = bm * 256 + ms * 128 + wm * 64 + fm * 16 + ((lane >> 4) * 4);
#pragma unroll
      for (int ns = 0; ns < 2; ++ns)
#pragma unroll
        for (int fn = 0; fn < 2; ++fn) {
          const int col = bn * 256 + ns * 128 + wn * 32 + fn * 16 + lb15;
          const float bv = bias ? bias[col] : 0.0f;
#pragma unroll
          for (int r = 0; r < 4; ++r)
            C[(size_t)(row0 + r) * N + col] = f2b(acc[ms][fm][ns][fn][r] + bv);
        }
    }
#undef SAg
#undef SBg
#undef LDA
#undef LDB
#undef MFMAQ
#undef TILEBODY
}

// ---------- kernel 4: fused scatter/gather + gates ----------
__global__ __launch_bounds__(256) void fused_epi(
    const u16* __restrict__ XO, const u16* __restrict__ HO,
    const float* __restrict__ h0, const float* __restrict__ c0,
    const int* __restrict__ idd, const int* __restrict__ idr,
    const int* __restrict__ idl, float* __restrict__ outh,
    float* __restrict__ outc, int b0) {
  __shared__ int listD[512], listR[512], listL[512];
  __shared__ int cnt[3];
  const int j = blockIdx.x;
  const int lb = blockIdx.y;
  const int b = b0 + lb;
  const int tid = threadIdx.x;
  const int lane = tid & 63;
  const int wave = tid >> 6;

  if (wave < 3) {
    const int* ids = (wave == 0 ? idd : (wave == 1 ? idr : idl)) + (size_t)b * 512;
    int* lst = (wave == 0 ? listD : (wave == 1 ? listR : listL));
    int base = 0;
#pragma unroll
    for (int c2 = 0; c2 < 8; ++c2) {
      int l = c2 * 64 + lane;
      int id = ids[l];
      u64 m = __ballot(id == j);
      if (id == j) {
        int pos = __popcll(m & ((1ull << lane) - 1ull));
        lst[base + pos] = l;
      }
      base += __popcll(m);
    }
    if (lane == 0) cnt[wave] = base;
  }
  __syncthreads();

  const int nD = cnt[0], nR = cnt[1], nL = cnt[2];
  const size_t grow = (size_t)b * 512 + j;
  const int k = tid * 4;

  if (!((nD > 0) && (j != 0))) {
    f32x4 hv = *(const f32x4*)(h0 + grow * 1024 + k);
    f32x4 cv = *(const f32x4*)(c0 + grow * 1024 + k);
    *(f32x4*)(outh + grow * 1024 + k) = hv;
    *(f32x4*)(outc + grow * 1024 + k) = cv;
    return;
  }

  const size_t lrow = (size_t)lb * 512 + j;
  const u16* xo = XO + lrow * 4096;
  f32x4 ai = ldb4(xo + k);
  f32x4 ao = ldb4(xo + 1024 + k);
  f32x4 au = ldb4(xo + 2048 + k);
  f32x4 fx = ldb4(xo + 3072 + k);

  for (int t = 0; t < nR; ++t) {
    const u16* hr = HO + ((size_t)lb * 512 + listR[t]) * 8192;
    ai += ldb4(hr + k);
    ao += ldb4(hr + 1024 + k);
    au += ldb4(hr + 2048 + k);
  }
  for (int t = 0; t < nL; ++t) {
    const u16* hl = HO + ((size_t)lb * 512 + listL[t]) * 8192;
    ai += ldb4(hl + 3072 + k);
    ao += ldb4(hl + 4096 + k);
    au += ldb4(hl + 5120 + k);
  }
  f32x4 gi = sigm4(ai), go = sigm4(ao), gu = tanh4(au);
  f32x4 c = gi * gu;
  for (int t = 0; t < nD; ++t) {
    int child = listD[t];
    int rr = idr[(size_t)b * 512 + child];
    int ll = idl[(size_t)b * 512 + child];
    f32x4 fpre = fx + ldb4(HO + ((size_t)lb * 512 + rr) * 8192 + 6144 + k) +
                 ldb4(HO + ((size_t)lb * 512 + ll) * 8192 + 7168 + k);
    f32x4 fg = sigm4(fpre);
    f32x4 cc = *(const f32x4*)(c0 + ((size_t)b * 512 + child) * 1024 + k);
    c += fg * cc;
  }
  f32x4 h = go * tanh4(c);
  *(f32x4*)(outh + grow * 1024 + k) = h;
  *(f32x4*)(outc + grow * 1024 + k) = c;
}

// ---------- host ----------
extern "C" void kernel_launch(void* const* d_in, const int* in_sizes, int n_in,
                              void* d_out, int out_size, void* d_ws,
                              size_t ws_size, hipStream_t stream) {
  const float* x = (const float*)d_in[0];
  const float* h0 = (const float*)d_in[1];
  const float* c0 = (const float*)d_in[2];
  const float* W_ioux = (const float*)d_in[3];
  const float* b_ioux = (const float*)d_in[4];
  const float* W_iouh_r = (const float*)d_in[5];
  const float* W_iouh_l = (const float*)d_in[6];
  const float* W_fx = (const float*)d_in[7];
  const float* b_fx = (const float*)d_in[8];
  const float* W_fh0 = (const float*)d_in[9];
  const float* W_fh1 = (const float*)d_in[10];
  const float* W_fh2 = (const float*)d_in[11];
  const float* W_fh3 = (const float*)d_in[12];
  const int* idd = (const int*)d_in[13];
  const int* idr = (const int*)d_in[14];
  const int* idl = (const int*)d_in[15];

  const size_t M = 16384;  // B*L
  char* p = (char*)d_ws;
  u16* Xb = (u16*)p;   p += M * 1024 * 2;
  u16* Hb = (u16*)p;   p += M * 1024 * 2;
  u16* WxT = (u16*)p;  p += (size_t)4096 * 1024 * 2;
  u16* WhT = (u16*)p;  p += (size_t)8192 * 1024 * 2;
  float* bcat = (float*)p; p += (size_t)4096 * 4;
  const size_t base_sz = (size_t)(p - (char*)d_ws);
  const size_t per_cb = (size_t)512 * 4096 * 2 + (size_t)512 * 8192 * 2;
  int CB = 32;
  while (CB > 1 && base_sz + (size_t)CB * per_cb > ws_size) CB >>= 1;
  u16* XO = (u16*)p;   p += (size_t)CB * 512 * 4096 * 2;
  u16* HO = (u16*)p;

  float* outh = (float*)d_out;
  float* outc = outh + M * 1024;

  cvt2_kernel<<<2048, 256, 0, stream>>>((const f32x4*)x, (const f32x4*)h0,
                                        (u16x4*)Xb, (u16x4*)Hb,
                                        (int)(M * 1024 / 4));
  packw_kernel<<<6144, 256, 0, stream>>>(W_ioux, b_ioux, W_iouh_r, W_iouh_l,
                                         W_fx, b_fx, W_fh0, W_fh1, W_fh2, W_fh3,
                                         WxT, WhT, bcat);

  const int nc = 32 / CB;
  for (int c = 0; c < nc; ++c) {
    const int mrows = CB * 512;
    const u16* Ax = Xb + (size_t)c * CB * 512 * 1024;
    const u16* Ah = Hb + (size_t)c * CB * 512 * 1024;
    gemm_bt<<<(mrows / 256) * (4096 / 256), 512, 0, stream>>>(Ax, WxT, XO, bcat,
                                                              4096, 1024 / 64);
    gemm_bt<<<(mrows / 256) * (8192 / 256), 512, 0, stream>>>(Ah, WhT, HO,
                                                              nullptr, 8192,
                                                              1024 / 64);
    fused_epi<<<dim3(512, CB), 256, 0, stream>>>(XO, HO, h0, c0, idd, idr, idl,
                                                 outh, outc, c * CB);
  }
}

// Round 9
// 576.837 us; speedup vs baseline: 1.1507x; 1.0038x over previous
//
#include <hip/hip_runtime.h>
#include <hip/hip_bf16.h>

typedef unsigned short u16;
typedef unsigned int u32;
typedef unsigned long long u64;
typedef float f32x4 __attribute__((ext_vector_type(4)));
typedef u16 u16x4 __attribute__((ext_vector_type(4)));
typedef u16 u16x8 __attribute__((ext_vector_type(8)));
typedef short s16x8 __attribute__((ext_vector_type(8)));

// ---------- helpers ----------
__device__ __forceinline__ u16 f2b(float f) {
  return __builtin_bit_cast(u16, __float2bfloat16(f));
}
__device__ __forceinline__ float b2f(u16 u) {
  return __builtin_bit_cast(float, ((u32)u) << 16);
}
__device__ __forceinline__ f32x4 ldb4(const u16* __restrict__ p) {
  u16x4 v = *(const u16x4*)p;
  f32x4 r;
#pragma unroll
  for (int i = 0; i < 4; ++i) r[i] = b2f(v[i]);
  return r;
}
__device__ __forceinline__ f32x4 sigm4(f32x4 x) {
  f32x4 r;
#pragma unroll
  for (int i = 0; i < 4; ++i) r[i] = 1.0f / (1.0f + __expf(-x[i]));
  return r;
}
__device__ __forceinline__ f32x4 tanh4(f32x4 x) {
  f32x4 r;
#pragma unroll
  for (int i = 0; i < 4; ++i) {
    float xx = fminf(fmaxf(x[i], -15.0f), 15.0f);
    float e = __expf(2.0f * xx);
    r[i] = (e - 1.0f) / (e + 1.0f);
  }
  return r;
}

__device__ __forceinline__ void gload_lds16(const void* g, void* l) {
  typedef __attribute__((address_space(1))) const u32 gq_t;
  typedef __attribute__((address_space(3))) u32 lq_t;
  gq_t* gp = (gq_t*)(u64)(size_t)g;
  lq_t* lp = (lq_t*)(u32)(size_t)l;
  __builtin_amdgcn_global_load_lds(gp, lp, 16, 0, 0);
}

// Builtin MFMA: compiler sees operand deps -> inserts its own COUNTED lgkm
// waits per-dependency, letting tail ds_reads drain under the MFMA stream.
__device__ __forceinline__ f32x4 mfma_b(u16x8 a, u16x8 b, f32x4 c) {
  return __builtin_amdgcn_mfma_f32_16x16x32_bf16(
      __builtin_bit_cast(s16x8, a), __builtin_bit_cast(s16x8, b), c, 0, 0, 0);
}

// ---------- kernel 1: cast x, h0 to bf16 ----------
__global__ __launch_bounds__(256) void cvt2_kernel(
    const f32x4* __restrict__ x, const f32x4* __restrict__ h,
    u16x4* __restrict__ xb, u16x4* __restrict__ hb, int n4) {
  for (int i = blockIdx.x * blockDim.x + threadIdx.x; i < n4;
       i += gridDim.x * blockDim.x) {
    f32x4 a = x[i], b = h[i];
    u16x4 ra, rb;
#pragma unroll
    for (int j = 0; j < 4; ++j) { ra[j] = f2b(a[j]); rb[j] = f2b(b[j]); }
    xb[i] = ra;
    hb[i] = rb;
  }
}

// ---------- kernel 2: pack + transpose weights to bf16 [N][K] ----------
__global__ __launch_bounds__(256) void packw_kernel(
    const float* __restrict__ W_ioux, const float* __restrict__ b_ioux,
    const float* __restrict__ W_iouh_r, const float* __restrict__ W_iouh_l,
    const float* __restrict__ W_fx, const float* __restrict__ b_fx,
    const float* __restrict__ W_fh0, const float* __restrict__ W_fh1,
    const float* __restrict__ W_fh2, const float* __restrict__ W_fh3,
    u16* __restrict__ WxT, u16* __restrict__ WhT, float* __restrict__ bcat) {
  const int t = blockIdx.x * 256 + threadIdx.x;
  const int NXW = 4096 * 128;
  float v[8];
  if (t < NXW) {
    const int n = t & 4095;
    const int k0 = (t >> 12) * 8;
    if (n < 3072) {
#pragma unroll
      for (int j = 0; j < 8; ++j) v[j] = W_ioux[(size_t)(k0 + j) * 3072 + n];
    } else {
#pragma unroll
      for (int j = 0; j < 8; ++j) v[j] = W_fx[(size_t)(k0 + j) * 1024 + (n - 3072)];
    }
    u16x8 o;
#pragma unroll
    for (int j = 0; j < 8; ++j) o[j] = f2b(v[j]);
    *(u16x8*)(WxT + (size_t)n * 1024 + k0) = o;
    if (k0 == 0) bcat[n] = (n < 3072) ? b_ioux[n] : b_fx[n - 3072];
  } else {
    const int u = t - NXW;
    const int m = u & 8191;
    const int k0 = (u >> 13) * 8;
    if (m < 3072) {
#pragma unroll
      for (int j = 0; j < 8; ++j) v[j] = W_iouh_r[(size_t)(k0 + j) * 3072 + m];
    } else if (m < 6144) {
#pragma unroll
      for (int j = 0; j < 8; ++j) v[j] = W_iouh_l[(size_t)(k0 + j) * 3072 + (m - 3072)];
    } else if (m < 7168) {
      const int c = m - 6144;
#pragma unroll
      for (int j = 0; j < 8; ++j)
        v[j] = W_fh0[(size_t)(k0 + j) * 1024 + c] + W_fh1[(size_t)(k0 + j) * 1024 + c];
    } else {
      const int c = m - 7168;
#pragma unroll
      for (int j = 0; j < 8; ++j)
        v[j] = W_fh2[(size_t)(k0 + j) * 1024 + c] + W_fh3[(size_t)(k0 + j) * 1024 + c];
    }
    u16x8 o;
#pragma unroll
    for (int j = 0; j < 8; ++j) o[j] = f2b(v[j]);
    *(u16x8*)(WhT + (size_t)m * 1024 + k0) = o;
  }
}

// ---------- kernel 3: 256x256 4-phase NT GEMM, compiler-counted lgkm -------
// 512 threads = 8 waves (2M x 4N), wave tile 128x64. LDS 128KB XOR-swizzled.
// Per phase: {ds_read frags, stage 2 gload_lds, setprio, 16 MFMA (compiler
// inserts minimal counted lgkm waits per operand), setprio, s_barrier}.
// ONE counted vmcnt(4) per K-tile (P4). NO manual lgkmcnt(0): the MFMA
// operand deps certify all reads complete before the phase-end barrier, and
// forcing a full drain before the first MFMA serializes read-drain with the
// MFMA stream (R8 counters: per-tile == read-time + MFMA-time exactly).

#define BARRIER __builtin_amdgcn_s_barrier()
#define VMCNT(n) asm volatile("s_waitcnt vmcnt(" #n ")")

__global__ __launch_bounds__(512, 2) void gemm_bt(
    const u16* __restrict__ A, const u16* __restrict__ Bt,
    u16* __restrict__ C, const float* __restrict__ bias, int N, int nk) {
  __shared__ u16 lds_u16[65536];  // 128 KB: A 2x32KB @0, B 2x32KB @65536
  char* ldsb = (char*)lds_u16;
  const int tid = threadIdx.x;
  const int lane = tid & 63;
  const int wave = tid >> 6;
  const int wm = wave >> 2, wn = wave & 3;
  const int K = nk * 64;

  // XCD-aware block swizzle (nwg % 8 == 0 by construction)
  const int nbn = N >> 8;
  const int nwg = gridDim.x;
  const int bid = blockIdx.x;
  const int swz = (bid & 7) * (nwg >> 3) + (bid >> 3);
  const int bm = swz / nbn, bn = swz % nbn;

  // staging source: inverse-XOR-swizzled so swizzled ds_reads see linear data
  const int srow = tid >> 3;
  const int ssw = (((tid & 7) * 16) ^ ((srow & 7) << 4)) >> 1;
  const u16* Ab = A + (size_t)(bm * 256 + srow) * K + ssw;
  const u16* Bb = Bt + (size_t)(bn * 256 + srow) * K + ssw;

#define SAg(PB, c, kt)                                          \
  gload_lds16(Ab + (size_t)(c) * 64 * K + (size_t)(kt) * 64,    \
              ldsb + (PB) + (c) * 8192 + tid * 16)
#define SBg(PB, c, kt)                                          \
  gload_lds16(Bb + (size_t)(c) * 64 * K + (size_t)(kt) * 64,    \
              ldsb + 65536 + (PB) + (c) * 8192 + tid * 16)

  // fragment read offsets (XOR swizzle depends only on lane)
  const int lb15 = lane & 15;
  const int lh16 = (lane >> 4) * 16;
  const int sw = (lane & 7) << 4;
  int a_off[2], b_off[2];
  a_off[0] = (wm * 64 + lb15) * 128 + (lh16 ^ sw);
  a_off[1] = (wm * 64 + lb15) * 128 + ((64 + lh16) ^ sw);
  b_off[0] = 65536 + (wn * 32 + lb15) * 128 + (lh16 ^ sw);
  b_off[1] = 65536 + (wn * 32 + lb15) * 128 + ((64 + lh16) ^ sw);

#define LDA(AR, PB, MS)                                                    \
  _Pragma("unroll") for (int fm = 0; fm < 4; ++fm) _Pragma("unroll")       \
      for (int kk = 0; kk < 2; ++kk) AR[fm][kk] =                          \
          *(const u16x8*)(ldsb + (PB) + a_off[kk] + (MS)*16384 + fm * 2048)
#define LDB(BR, PB, NS)                                                    \
  _Pragma("unroll") for (int fn = 0; fn < 2; ++fn) _Pragma("unroll")       \
      for (int kk = 0; kk < 2; ++kk) BR[fn][kk] =                          \
          *(const u16x8*)(ldsb + (PB) + b_off[kk] + (NS)*16384 + fn * 2048)
#define MFMAQ(MS, NS, AR, BR)                                              \
  _Pragma("unroll") for (int kk = 0; kk < 2; ++kk) _Pragma("unroll")       \
      for (int fm = 0; fm < 4; ++fm) _Pragma("unroll")                     \
      for (int fn = 0; fn < 2; ++fn) acc[MS][fm][NS][fn] =                 \
          mfma_b(AR[fm][kk], BR[fn][kk], acc[MS][fm][NS][fn])

  u16x8 ar0[4][2], ar1[4][2], br0[2][2], br1[2][2];
  f32x4 acc[2][4][2][2] = {};

  // prologue: tile0 all 8 chunks -> buf0; tile1's A01,B23 -> buf1
  {
    const int s1 = (nk > 1) ? 1 : 0;
    SAg(0, 0, 0); SAg(0, 1, 0); SAg(0, 2, 0); SAg(0, 3, 0);
    SBg(0, 0, 0); SBg(0, 1, 0); SBg(0, 2, 0); SBg(0, 3, 0);
    SAg(32768, 0, s1); SAg(32768, 1, s1);
    SBg(32768, 2, s1); SBg(32768, 3, s1);
  }
  VMCNT(4);  // tile0 landed; tile1's 4 stay in flight
  BARRIER;

  // TILEBODY: literal buffer byte-offset PB (0 or 32768); QB = other buffer.
  // ONE barrier per phase (at phase end); no manual lgkm waits.
#define TILEBODY(PB, QB, Tcur)                                          \
  {                                                                     \
    const int s1 = ((Tcur) + 1 < nk) ? (Tcur) + 1 : nk - 1;             \
    const int s2 = ((Tcur) + 2 < nk) ? (Tcur) + 2 : nk - 1;             \
    /* P1 (m0,n0): read br0,ar0 from PB; stage QB A23 (tile T+1) */     \
    SAg(QB, 2, s1); SAg(QB, 3, s1);                                     \
    LDB(br0, PB, 0);                                                    \
    LDA(ar0, PB, 0);                                                    \
    __builtin_amdgcn_s_setprio(1);                                      \
    MFMAQ(0, 0, ar0, br0);                                              \
    __builtin_amdgcn_s_setprio(0);                                      \
    BARRIER;                                                            \
    /* P2 (m0,n1): read br1; stage QB B01 (tile T+1) */                 \
    SBg(QB, 0, s1); SBg(QB, 1, s1);                                     \
    LDB(br1, PB, 1);                                                    \
    __builtin_amdgcn_s_setprio(1);                                      \
    MFMAQ(0, 1, ar0, br1);                                              \
    __builtin_amdgcn_s_setprio(0);                                      \
    BARRIER;                                                            \
    /* P3 (m1,n1): read ar1; stage PB A01 (tile T+2) */                 \
    SAg(PB, 0, s2); SAg(PB, 1, s2);                                     \
    LDA(ar1, PB, 1);                                                    \
    __builtin_amdgcn_s_setprio(1);                                      \
    MFMAQ(1, 1, ar1, br1);                                              \
    __builtin_amdgcn_s_setprio(0);                                      \
    BARRIER;                                                            \
    /* P4 (m1,n0): reuse ar1,br0; stage PB B23 (tile T+2); vmcnt(4) */  \
    SBg(PB, 2, s2); SBg(PB, 3, s2);                                     \
    __builtin_amdgcn_s_setprio(1);                                      \
    MFMAQ(1, 0, ar1, br0);                                              \
    __builtin_amdgcn_s_setprio(0);                                      \
    VMCNT(4);                                                           \
    BARRIER;                                                            \
  }

  for (int T = 0; T < nk; T += 2) {
    TILEBODY(0, 32768, T);
    TILEBODY(32768, 0, T + 1);
  }
  VMCNT(0);

  // epilogue: wave rows {wm*64.., 128+wm*64..}, cols {wn*32.., 128+wn*32..}
#pragma unroll
  for (int ms = 0; ms < 2; ++ms)
#pragma unroll
    for (int fm = 0; fm < 4; ++fm) {
      const int row0 = bm * 256 + ms * 128 + wm * 64 + fm * 16 + ((lane >> 4) * 4);
#pragma unroll
      for (int ns = 0; ns < 2; ++ns)
#pragma unroll
        for (int fn = 0; fn < 2; ++fn) {
          const int col = bn * 256 + ns * 128 + wn * 32 + fn * 16 + lb15;
          const float bv = bias ? bias[col] : 0.0f;
#pragma unroll
          for (int r = 0; r < 4; ++r)
            C[(size_t)(row0 + r) * N + col] = f2b(acc[ms][fm][ns][fn][r] + bv);
        }
    }
#undef SAg
#undef SBg
#undef LDA
#undef LDB
#undef MFMAQ
#undef TILEBODY
}

// ---------- kernel 4: fused scatter/gather + gates ----------
__global__ __launch_bounds__(256) void fused_epi(
    const u16* __restrict__ XO, const u16* __restrict__ HO,
    const float* __restrict__ h0, const float* __restrict__ c0,
    const int* __restrict__ idd, const int* __restrict__ idr,
    const int* __restrict__ idl, float* __restrict__ outh,
    float* __restrict__ outc, int b0) {
  __shared__ int listD[512], listR[512], listL[512];
  __shared__ int cnt[3];
  const int j = blockIdx.x;
  const int lb = blockIdx.y;
  const int b = b0 + lb;
  const int tid = threadIdx.x;
  const int lane = tid & 63;
  const int wave = tid >> 6;

  if (wave < 3) {
    const int* ids = (wave == 0 ? idd : (wave == 1 ? idr : idl)) + (size_t)b * 512;
    int* lst = (wave == 0 ? listD : (wave == 1 ? listR : listL));
    int base = 0;
#pragma unroll
    for (int c2 = 0; c2 < 8; ++c2) {
      int l = c2 * 64 + lane;
      int id = ids[l];
      u64 m = __ballot(id == j);
      if (id == j) {
        int pos = __popcll(m & ((1ull << lane) - 1ull));
        lst[base + pos] = l;
      }
      base += __popcll(m);
    }
    if (lane == 0) cnt[wave] = base;
  }
  __syncthreads();

  const int nD = cnt[0], nR = cnt[1], nL = cnt[2];
  const size_t grow = (size_t)b * 512 + j;
  const int k = tid * 4;

  if (!((nD > 0) && (j != 0))) {
    f32x4 hv = *(const f32x4*)(h0 + grow * 1024 + k);
    f32x4 cv = *(const f32x4*)(c0 + grow * 1024 + k);
    *(f32x4*)(outh + grow * 1024 + k) = hv;
    *(f32x4*)(outc + grow * 1024 + k) = cv;
    return;
  }

  const size_t lrow = (size_t)lb * 512 + j;
  const u16* xo = XO + lrow * 4096;
  f32x4 ai = ldb4(xo + k);
  f32x4 ao = ldb4(xo + 1024 + k);
  f32x4 au = ldb4(xo + 2048 + k);
  f32x4 fx = ldb4(xo + 3072 + k);

  for (int t = 0; t < nR; ++t) {
    const u16* hr = HO + ((size_t)lb * 512 + listR[t]) * 8192;
    ai += ldb4(hr + k);
    ao += ldb4(hr + 1024 + k);
    au += ldb4(hr + 2048 + k);
  }
  for (int t = 0; t < nL; ++t) {
    const u16* hl = HO + ((size_t)lb * 512 + listL[t]) * 8192;
    ai += ldb4(hl + 3072 + k);
    ao += ldb4(hl + 4096 + k);
    au += ldb4(hl + 5120 + k);
  }
  f32x4 gi = sigm4(ai), go = sigm4(ao), gu = tanh4(au);
  f32x4 c = gi * gu;
  for (int t = 0; t < nD; ++t) {
    int child = listD[t];
    int rr = idr[(size_t)b * 512 + child];
    int ll = idl[(size_t)b * 512 + child];
    f32x4 fpre = fx + ldb4(HO + ((size_t)lb * 512 + rr) * 8192 + 6144 + k) +
                 ldb4(HO + ((size_t)lb * 512 + ll) * 8192 + 7168 + k);
    f32x4 fg = sigm4(fpre);
    f32x4 cc = *(const f32x4*)(c0 + ((size_t)b * 512 + child) * 1024 + k);
    c += fg * cc;
  }
  f32x4 h = go * tanh4(c);
  *(f32x4*)(outh + grow * 1024 + k) = h;
  *(f32x4*)(outc + grow * 1024 + k) = c;
}

// ---------- host ----------
extern "C" void kernel_launch(void* const* d_in, const int* in_sizes, int n_in,
                              void* d_out, int out_size, void* d_ws,
                              size_t ws_size, hipStream_t stream) {
  const float* x = (const float*)d_in[0];
  const float* h0 = (const float*)d_in[1];
  const float* c0 = (const float*)d_in[2];
  const float* W_ioux = (const float*)d_in[3];
  const float* b_ioux = (const float*)d_in[4];
  const float* W_iouh_r = (const float*)d_in[5];
  const float* W_iouh_l = (const float*)d_in[6];
  const float* W_fx = (const float*)d_in[7];
  const float* b_fx = (const float*)d_in[8];
  const float* W_fh0 = (const float*)d_in[9];
  const float* W_fh1 = (const float*)d_in[10];
  const float* W_fh2 = (const float*)d_in[11];
  const float* W_fh3 = (const float*)d_in[12];
  const int* idd = (const int*)d_in[13];
  const int* idr = (const int*)d_in[14];
  const int* idl = (const int*)d_in[15];

  const size_t M = 16384;  // B*L
  char* p = (char*)d_ws;
  u16* Xb = (u16*)p;   p += M * 1024 * 2;
  u16* Hb = (u16*)p;   p += M * 1024 * 2;
  u16* WxT = (u16*)p;  p += (size_t)4096 * 1024 * 2;
  u16* WhT = (u16*)p;  p += (size_t)8192 * 1024 * 2;
  float* bcat = (float*)p; p += (size_t)4096 * 4;
  const size_t base_sz = (size_t)(p - (char*)d_ws);
  const size_t per_cb = (size_t)512 * 4096 * 2 + (size_t)512 * 8192 * 2;
  int CB = 32;
  while (CB > 1 && base_sz + (size_t)CB * per_cb > ws_size) CB >>= 1;
  u16* XO = (u16*)p;   p += (size_t)CB * 512 * 4096 * 2;
  u16* HO = (u16*)p;

  float* outh = (float*)d_out;
  float* outc = outh + M * 1024;

  cvt2_kernel<<<2048, 256, 0, stream>>>((const f32x4*)x, (const f32x4*)h0,
                                        (u16x4*)Xb, (u16x4*)Hb,
                                        (int)(M * 1024 / 4));
  packw_kernel<<<6144, 256, 0, stream>>>(W_ioux, b_ioux, W_iouh_r, W_iouh_l,
                                         W_fx, b_fx, W_fh0, W_fh1, W_fh2, W_fh3,
                                         WxT, WhT, bcat);

  const int nc = 32 / CB;
  for (int c = 0; c < nc; ++c) {
    const int mrows = CB * 512;
    const u16* Ax = Xb + (size_t)c * CB * 512 * 1024;
    const u16* Ah = Hb + (size_t)c * CB * 512 * 1024;
    gemm_bt<<<(mrows / 256) * (4096 / 256), 512, 0, stream>>>(Ax, WxT, XO, bcat,
                                                              4096, 1024 / 64);
    gemm_bt<<<(mrows / 256) * (8192 / 256), 512, 0, stream>>>(Ah, WhT, HO,
                                                              nullptr, 8192,
                                                              1024 / 64);
    fused_epi<<<dim3(512, CB), 256, 0, stream>>>(XO, HO, h0, c0, idd, idr, idl,
                                                 outh, outc, c * CB);
  }
}

// Round 10
// 574.635 us; speedup vs baseline: 1.1551x; 1.0038x over previous
//
#include <hip/hip_runtime.h>
#include <hip/hip_bf16.h>

typedef unsigned short u16;
typedef unsigned int u32;
typedef unsigned long long u64;
typedef float f32x4 __attribute__((ext_vector_type(4)));
typedef u16 u16x4 __attribute__((ext_vector_type(4)));
typedef u16 u16x8 __attribute__((ext_vector_type(8)));
typedef short s16x8 __attribute__((ext_vector_type(8)));

// ---------- helpers ----------
__device__ __forceinline__ u16 f2b(float f) {
  return __builtin_bit_cast(u16, __float2bfloat16(f));
}
__device__ __forceinline__ float b2f(u16 u) {
  return __builtin_bit_cast(float, ((u32)u) << 16);
}
__device__ __forceinline__ f32x4 ldb4(const u16* __restrict__ p) {
  u16x4 v = *(const u16x4*)p;
  f32x4 r;
#pragma unroll
  for (int i = 0; i < 4; ++i) r[i] = b2f(v[i]);
  return r;
}
__device__ __forceinline__ u16x4 cvt4(f32x4 v) {
  u16x4 r;
#pragma unroll
  for (int i = 0; i < 4; ++i) r[i] = f2b(v[i]);
  return r;
}
__device__ __forceinline__ f32x4 sigm4(f32x4 x) {
  f32x4 r;
#pragma unroll
  for (int i = 0; i < 4; ++i) r[i] = 1.0f / (1.0f + __expf(-x[i]));
  return r;
}
__device__ __forceinline__ f32x4 tanh4(f32x4 x) {
  f32x4 r;
#pragma unroll
  for (int i = 0; i < 4; ++i) {
    float xx = fminf(fmaxf(x[i], -15.0f), 15.0f);
    float e = __expf(2.0f * xx);
    r[i] = (e - 1.0f) / (e + 1.0f);
  }
  return r;
}

__device__ __forceinline__ void gload_lds16(const void* g, void* l) {
  typedef __attribute__((address_space(1))) const u32 gq_t;
  typedef __attribute__((address_space(3))) u32 lq_t;
  gq_t* gp = (gq_t*)(u64)(size_t)g;
  lq_t* lp = (lq_t*)(u32)(size_t)l;
  __builtin_amdgcn_global_load_lds(gp, lp, 16, 0, 0);
}

__device__ __forceinline__ f32x4 mfma_b(u16x8 a, u16x8 b, f32x4 c) {
  return __builtin_amdgcn_mfma_f32_16x16x32_bf16(
      __builtin_bit_cast(s16x8, a), __builtin_bit_cast(s16x8, b), c, 0, 0, 0);
}

// ---------- kernel 1: cast x to bf16 ----------
__global__ __launch_bounds__(256) void cvtx_kernel(
    const f32x4* __restrict__ x, u16x4* __restrict__ xb, int n4) {
  for (int i = blockIdx.x * blockDim.x + threadIdx.x; i < n4;
       i += gridDim.x * blockDim.x) {
    f32x4 a = x[i];
    xb[i] = cvt4(a);
  }
}

// ---------- kernel 2: prep — HR/HL scatter-aggregates, Gx/Gr/Gl gathers,
// updated flags. One block per (j=node, b=batch). ----------
__global__ __launch_bounds__(256) void prep_kernel(
    const float* __restrict__ x, const float* __restrict__ h0,
    const int* __restrict__ idd, const int* __restrict__ idr,
    const int* __restrict__ idl, u16* __restrict__ HR, u16* __restrict__ HL,
    u16* __restrict__ Gx, u16* __restrict__ Gr, u16* __restrict__ Gl,
    int* __restrict__ updated) {
  __shared__ int listR[512], listL[512];
  __shared__ int cnt[3];
  const int j = blockIdx.x;
  const int b = blockIdx.y;
  const int tid = threadIdx.x;
  const int lane = tid & 63;
  const int wave = tid >> 6;

  if (wave < 3) {
    const int* ids = (wave == 0 ? idd : (wave == 1 ? idr : idl)) + (size_t)b * 512;
    int* lst = (wave == 1 ? listR : listL);
    int base = 0;
#pragma unroll
    for (int c2 = 0; c2 < 8; ++c2) {
      int l = c2 * 64 + lane;
      int id = ids[l];
      u64 m = __ballot(id == j);
      if (wave > 0 && id == j) {
        int pos = __popcll(m & ((1ull << lane) - 1ull));
        lst[base + pos] = l;
      }
      base += __popcll(m);
    }
    if (lane == 0) cnt[wave] = base;
  }
  __syncthreads();

  const size_t grow = (size_t)b * 512 + j;
  if (tid == 0) updated[grow] = (cnt[0] > 0 && j != 0) ? 1 : 0;

  const int k = tid * 4;
  const size_t bbase = (size_t)b * 512;

  // HR = sum of h0 rows with dr(l)==j ; HL likewise with dl
  f32x4 sr = {0.f, 0.f, 0.f, 0.f};
  for (int t = 0; t < cnt[1]; ++t)
    sr += *(const f32x4*)(h0 + (bbase + listR[t]) * 1024 + k);
  *(u16x4*)(HR + grow * 1024 + k) = cvt4(sr);

  f32x4 sl = {0.f, 0.f, 0.f, 0.f};
  for (int t = 0; t < cnt[2]; ++t)
    sl += *(const f32x4*)(h0 + (bbase + listL[t]) * 1024 + k);
  *(u16x4*)(HL + grow * 1024 + k) = cvt4(sl);

  // gathers at l=j: Gx = x[d(l)], Gr = h0[dr(l)], Gl = h0[dl(l)]
  const int dd = idd[grow], rr = idr[grow], ll = idl[grow];
  *(u16x4*)(Gx + grow * 1024 + k) =
      cvt4(*(const f32x4*)(x + (bbase + dd) * 1024 + k));
  *(u16x4*)(Gr + grow * 1024 + k) =
      cvt4(*(const f32x4*)(h0 + (bbase + rr) * 1024 + k));
  *(u16x4*)(Gl + grow * 1024 + k) =
      cvt4(*(const f32x4*)(h0 + (bbase + ll) * 1024 + k));
}

// ---------- kernel 3: compact — rowidx of updated rows (single block) ------
__global__ __launch_bounds__(1024) void compact_kernel(
    const int* __restrict__ updated, int* __restrict__ rowidx,
    int* __restrict__ mc) {
  __shared__ int sc[1024];
  const int t = threadIdx.x;
  int fl[16];
  int cl = 0;
#pragma unroll
  for (int i = 0; i < 16; ++i) {
    fl[i] = updated[t * 16 + i];
    cl += fl[i];
  }
  sc[t] = cl;
  __syncthreads();
  for (int d = 1; d < 1024; d <<= 1) {
    int v = sc[t];
    int add = (t >= d) ? sc[t - d] : 0;
    __syncthreads();
    sc[t] = v + add;
    __syncthreads();
  }
  const int Mc = sc[1023];
  int pos = sc[t] - cl;  // exclusive prefix
#pragma unroll
  for (int i = 0; i < 16; ++i)
    if (fl[i]) rowidx[pos++] = t * 16 + i;
  for (int s = Mc + t; s < 16384; s += 1024) rowidx[s] = 0;
  if (t == 0) mc[0] = Mc;
}

// ---------- kernel 4: pack weights: WIOUT[3072][3072], WFT[1024][3072] -----
// WIOUT row n, k: k<1024 -> W_ioux[k][n]; <2048 -> W_iouh_r; else W_iouh_l
// WFT   row n, k: k<1024 -> W_fx[k][n]; <2048 -> Wfh0+Wfh1; else Wfh2+Wfh3
__global__ __launch_bounds__(256) void packw_kernel(
    const float* __restrict__ W_ioux, const float* __restrict__ W_iouh_r,
    const float* __restrict__ W_iouh_l, const float* __restrict__ W_fx,
    const float* __restrict__ W_fh0, const float* __restrict__ W_fh1,
    const float* __restrict__ W_fh2, const float* __restrict__ W_fh3,
    u16* __restrict__ WIOUT, u16* __restrict__ WFT) {
  const int t = blockIdx.x * 256 + threadIdx.x;
  const int NIOU = 3072 * 384;
  float v[8];
  if (t < NIOU) {
    const int n = t % 3072;
    const int k0 = (t / 3072) * 8;
    if (k0 < 1024) {
#pragma unroll
      for (int i = 0; i < 8; ++i) v[i] = W_ioux[(size_t)(k0 + i) * 3072 + n];
    } else if (k0 < 2048) {
#pragma unroll
      for (int i = 0; i < 8; ++i) v[i] = W_iouh_r[(size_t)(k0 - 1024 + i) * 3072 + n];
    } else {
#pragma unroll
      for (int i = 0; i < 8; ++i) v[i] = W_iouh_l[(size_t)(k0 - 2048 + i) * 3072 + n];
    }
    u16x8 o;
#pragma unroll
    for (int i = 0; i < 8; ++i) o[i] = f2b(v[i]);
    *(u16x8*)(WIOUT + (size_t)n * 3072 + k0) = o;
  } else {
    const int u = t - NIOU;
    const int n = u & 1023;
    const int k0 = (u >> 10) * 8;
    if (k0 < 1024) {
#pragma unroll
      for (int i = 0; i < 8; ++i) v[i] = W_fx[(size_t)(k0 + i) * 1024 + n];
    } else if (k0 < 2048) {
#pragma unroll
      for (int i = 0; i < 8; ++i)
        v[i] = W_fh0[(size_t)(k0 - 1024 + i) * 1024 + n] +
               W_fh1[(size_t)(k0 - 1024 + i) * 1024 + n];
    } else {
#pragma unroll
      for (int i = 0; i < 8; ++i)
        v[i] = W_fh2[(size_t)(k0 - 2048 + i) * 1024 + n] +
               W_fh3[(size_t)(k0 - 2048 + i) * 1024 + n];
    }
    u16x8 o;
#pragma unroll
    for (int i = 0; i < 8; ++i) o[i] = f2b(v[i]);
    *(u16x8*)(WFT + (size_t)n * 3072 + k0) = o;
  }
}

// ---------- kernel 5: 256x256 4-phase NT GEMM (R9 champion schedule) -------
// A is virtual [*,3072]: kt<16 -> A0, kt<32 -> A1, else A2 (each [*,1024]).
// Optional rid row-gather (compaction); optional mc early-exit.
#define BARRIER __builtin_amdgcn_s_barrier()
#define VMCNT(n) asm volatile("s_waitcnt vmcnt(" #n ")")

__device__ __forceinline__ const u16* asel(const u16* A0, const u16* A1,
                                           const u16* A2, int kt) {
  return kt < 16 ? A0 : (kt < 32 ? A1 : A2);
}

__global__ __launch_bounds__(512, 2) void gemm3(
    const u16* __restrict__ A0, const u16* __restrict__ A1,
    const u16* __restrict__ A2, const u16* __restrict__ Bt,
    u16* __restrict__ C, const float* __restrict__ bias, int N,
    const int* __restrict__ rid, const int* __restrict__ mc) {
  const int nk = 48;  // K = 3072
  __shared__ u16 lds_u16[65536];  // 128 KB: A 2x32KB @0, B 2x32KB @65536
  char* ldsb = (char*)lds_u16;
  const int tid = threadIdx.x;
  const int lane = tid & 63;
  const int wave = tid >> 6;
  const int wm = wave >> 2, wn = wave & 3;

  // XCD-aware block swizzle (nwg % 8 == 0 by construction)
  const int nbn = N >> 8;
  const int nwg = gridDim.x;
  const int bid = blockIdx.x;
  const int swz = (bid & 7) * (nwg >> 3) + (bid >> 3);
  const int bm = swz / nbn, bn = swz % nbn;

  if (mc) {  // compaction: blocks past the padded row count exit (uniform)
    const int McPad = (mc[0] + 255) & ~255;
    if (bm * 256 >= McPad) return;
  }

  // staging source: inverse-XOR-swizzled so swizzled ds_reads see linear data
  const int srow = tid >> 3;
  const int ssw = (((tid & 7) * 16) ^ ((srow & 7) << 4)) >> 1;
  int rr4[4];
#pragma unroll
  for (int c = 0; c < 4; ++c) {
    int r = bm * 256 + c * 64 + srow;
    rr4[c] = rid ? rid[r] : r;
  }
  const u16* Bb = Bt + (size_t)(bn * 256 + srow) * 3072 + ssw;

#define SAg(PB, c, kt)                                                   \
  gload_lds16(asel(A0, A1, A2, (kt)) + (size_t)rr4[c] * 1024 +           \
                  ((kt) & 15) * 64 + ssw,                                \
              ldsb + (PB) + (c) * 8192 + tid * 16)
#define SBg(PB, c, kt)                                                   \
  gload_lds16(Bb + (size_t)(c) * 64 * 3072 + (size_t)(kt) * 64,          \
              ldsb + 65536 + (PB) + (c) * 8192 + tid * 16)

  // fragment read offsets (XOR swizzle depends only on lane)
  const int lb15 = lane & 15;
  const int lh16 = (lane >> 4) * 16;
  const int sw = (lane & 7) << 4;
  int a_off[2], b_off[2];
  a_off[0] = (wm * 64 + lb15) * 128 + (lh16 ^ sw);
  a_off[1] = (wm * 64 + lb15) * 128 + ((64 + lh16) ^ sw);
  b_off[0] = 65536 + (wn * 32 + lb15) * 128 + (lh16 ^ sw);
  b_off[1] = 65536 + (wn * 32 + lb15) * 128 + ((64 + lh16) ^ sw);

#define LDA(AR, PB, MS)                                                    \
  _Pragma("unroll") for (int fm = 0; fm < 4; ++fm) _Pragma("unroll")       \
      for (int kk = 0; kk < 2; ++kk) AR[fm][kk] =                          \
          *(const u16x8*)(ldsb + (PB) + a_off[kk] + (MS)*16384 + fm * 2048)
#define LDB(BR, PB, NS)                                                    \
  _Pragma("unroll") for (int fn = 0; fn < 2; ++fn) _Pragma("unroll")       \
      for (int kk = 0; kk < 2; ++kk) BR[fn][kk] =                          \
          *(const u16x8*)(ldsb + (PB) + b_off[kk] + (NS)*16384 + fn * 2048)
#define MFMAQ(MS, NS, AR, BR)                                              \
  _Pragma("unroll") for (int kk = 0; kk < 2; ++kk) _Pragma("unroll")       \
      for (int fm = 0; fm < 4; ++fm) _Pragma("unroll")                     \
      for (int fn = 0; fn < 2; ++fn) acc[MS][fm][NS][fn] =                 \
          mfma_b(AR[fm][kk], BR[fn][kk], acc[MS][fm][NS][fn])

  u16x8 ar0[4][2], ar1[4][2], br0[2][2], br1[2][2];
  f32x4 acc[2][4][2][2] = {};

  // prologue: tile0 all 8 chunks -> buf0; tile1's A01,B23 -> buf1
  SAg(0, 0, 0); SAg(0, 1, 0); SAg(0, 2, 0); SAg(0, 3, 0);
  SBg(0, 0, 0); SBg(0, 1, 0); SBg(0, 2, 0); SBg(0, 3, 0);
  SAg(32768, 0, 1); SAg(32768, 1, 1);
  SBg(32768, 2, 1); SBg(32768, 3, 1);
  VMCNT(4);
  BARRIER;

#define TILEBODY(PB, QB, Tcur)                                          \
  {                                                                     \
    const int s1 = ((Tcur) + 1 < nk) ? (Tcur) + 1 : nk - 1;             \
    const int s2 = ((Tcur) + 2 < nk) ? (Tcur) + 2 : nk - 1;             \
    SAg(QB, 2, s1); SAg(QB, 3, s1);                                     \
    LDB(br0, PB, 0);                                                    \
    LDA(ar0, PB, 0);                                                    \
    __builtin_amdgcn_s_setprio(1);                                      \
    MFMAQ(0, 0, ar0, br0);                                              \
    __builtin_amdgcn_s_setprio(0);                                      \
    BARRIER;                                                            \
    SBg(QB, 0, s1); SBg(QB, 1, s1);                                     \
    LDB(br1, PB, 1);                                                    \
    __builtin_amdgcn_s_setprio(1);                                      \
    MFMAQ(0, 1, ar0, br1);                                              \
    __builtin_amdgcn_s_setprio(0);                                      \
    BARRIER;                                                            \
    SAg(PB, 0, s2); SAg(PB, 1, s2);                                     \
    LDA(ar1, PB, 1);                                                    \
    __builtin_amdgcn_s_setprio(1);                                      \
    MFMAQ(1, 1, ar1, br1);                                              \
    __builtin_amdgcn_s_setprio(0);                                      \
    BARRIER;                                                            \
    SBg(PB, 2, s2); SBg(PB, 3, s2);                                     \
    __builtin_amdgcn_s_setprio(1);                                      \
    MFMAQ(1, 0, ar1, br0);                                              \
    __builtin_amdgcn_s_setprio(0);                                      \
    VMCNT(4);                                                           \
    BARRIER;                                                            \
  }

  for (int T = 0; T < nk; T += 2) {
    TILEBODY(0, 32768, T);
    TILEBODY(32768, 0, T + 1);
  }
  VMCNT(0);

  // epilogue: row lookup via rid; bias per col
#pragma unroll
  for (int ms = 0; ms < 2; ++ms)
#pragma unroll
    for (int fm = 0; fm < 4; ++fm)
#pragma unroll
      for (int r = 0; r < 4; ++r) {
        const int trow = ms * 128 + wm * 64 + fm * 16 + ((lane >> 4) * 4) + r;
        const int row = rid ? rid[bm * 256 + trow] : bm * 256 + trow;
        const size_t ro = (size_t)row * N;
#pragma unroll
        for (int ns = 0; ns < 2; ++ns)
#pragma unroll
          for (int fn = 0; fn < 2; ++fn) {
            const int col = bn * 256 + ns * 128 + wn * 32 + fn * 16 + lb15;
            const float bv = bias ? bias[col] : 0.0f;
            C[ro + col] = f2b(acc[ms][fm][ns][fn][r] + bv);
          }
      }
#undef SAg
#undef SBg
#undef LDA
#undef LDB
#undef MFMAQ
#undef TILEBODY
}

// ---------- kernel 6: epilogue — gates + fc scatter (D-list only) ----------
__global__ __launch_bounds__(256) void epi_kernel(
    const u16* __restrict__ IOU, const u16* __restrict__ F,
    const float* __restrict__ h0, const float* __restrict__ c0,
    const int* __restrict__ idd, float* __restrict__ outh,
    float* __restrict__ outc) {
  __shared__ int listD[512];
  __shared__ int cnt0;
  const int j = blockIdx.x;
  const int b = blockIdx.y;
  const int tid = threadIdx.x;
  const int lane = tid & 63;
  const int wave = tid >> 6;

  if (wave == 0) {
    const int* ids = idd + (size_t)b * 512;
    int base = 0;
#pragma unroll
    for (int c2 = 0; c2 < 8; ++c2) {
      int l = c2 * 64 + lane;
      int id = ids[l];
      u64 m = __ballot(id == j);
      if (id == j) {
        int pos = __popcll(m & ((1ull << lane) - 1ull));
        listD[base + pos] = l;
      }
      base += __popcll(m);
    }
    if (lane == 0) cnt0 = base;
  }
  __syncthreads();

  const int nD = cnt0;
  const size_t grow = (size_t)b * 512 + j;
  const int k = tid * 4;

  if (!((nD > 0) && (j != 0))) {  // not updated: pass through
    f32x4 hv = *(const f32x4*)(h0 + grow * 1024 + k);
    f32x4 cv = *(const f32x4*)(c0 + grow * 1024 + k);
    *(f32x4*)(outh + grow * 1024 + k) = hv;
    *(f32x4*)(outc + grow * 1024 + k) = cv;
    return;
  }

  const u16* io = IOU + grow * 3072;
  f32x4 gi = sigm4(ldb4(io + k));
  f32x4 go = sigm4(ldb4(io + 1024 + k));
  f32x4 gu = tanh4(ldb4(io + 2048 + k));
  f32x4 c = gi * gu;
  for (int t = 0; t < nD; ++t) {
    const size_t crow = (size_t)b * 512 + listD[t];
    f32x4 fg = sigm4(ldb4(F + crow * 1024 + k));  // b_fx folded in GEMM
    f32x4 cc = *(const f32x4*)(c0 + crow * 1024 + k);
    c += fg * cc;
  }
  f32x4 h = go * tanh4(c);
  *(f32x4*)(outh + grow * 1024 + k) = h;
  *(f32x4*)(outc + grow * 1024 + k) = c;
}

// ---------- host ----------
extern "C" void kernel_launch(void* const* d_in, const int* in_sizes, int n_in,
                              void* d_out, int out_size, void* d_ws,
                              size_t ws_size, hipStream_t stream) {
  const float* x = (const float*)d_in[0];
  const float* h0 = (const float*)d_in[1];
  const float* c0 = (const float*)d_in[2];
  const float* W_ioux = (const float*)d_in[3];
  const float* b_ioux = (const float*)d_in[4];
  const float* W_iouh_r = (const float*)d_in[5];
  const float* W_iouh_l = (const float*)d_in[6];
  const float* W_fx = (const float*)d_in[7];
  const float* b_fx = (const float*)d_in[8];
  const float* W_fh0 = (const float*)d_in[9];
  const float* W_fh1 = (const float*)d_in[10];
  const float* W_fh2 = (const float*)d_in[11];
  const float* W_fh3 = (const float*)d_in[12];
  const int* idd = (const int*)d_in[13];
  const int* idr = (const int*)d_in[14];
  const int* idl = (const int*)d_in[15];

  const size_t M = 16384;  // B*L
  char* p = (char*)d_ws;
  u16* Xb = (u16*)p;   p += M * 1024 * 2;
  u16* Gx = (u16*)p;   p += M * 1024 * 2;
  u16* HRb = (u16*)p;  p += M * 1024 * 2;
  u16* HLb = (u16*)p;  p += M * 1024 * 2;
  u16* Grb = (u16*)p;  p += M * 1024 * 2;
  u16* Glb = (u16*)p;  p += M * 1024 * 2;
  u16* WIOUT = (u16*)p; p += (size_t)3072 * 3072 * 2;
  u16* WFT = (u16*)p;   p += (size_t)1024 * 3072 * 2;
  u16* IOU = (u16*)p;   p += M * 3072 * 2;
  u16* F = (u16*)p;     p += M * 1024 * 2;
  int* updated = (int*)p; p += M * 4;
  int* rowidx = (int*)p;  p += M * 4;
  int* mc = (int*)p;      p += 64;

  float* outh = (float*)d_out;
  float* outc = outh + M * 1024;

  cvtx_kernel<<<2048, 256, 0, stream>>>((const f32x4*)x, (u16x4*)Xb,
                                        (int)(M * 1024 / 4));
  prep_kernel<<<dim3(512, 32), 256, 0, stream>>>(x, h0, idd, idr, idl, HRb,
                                                 HLb, Gx, Grb, Glb, updated);
  compact_kernel<<<1, 1024, 0, stream>>>(updated, rowidx, mc);
  packw_kernel<<<6144, 256, 0, stream>>>(W_ioux, W_iouh_r, W_iouh_l, W_fx,
                                         W_fh0, W_fh1, W_fh2, W_fh3, WIOUT,
                                         WFT);
  // F = [Gx|Gr|Gl] @ WFT^T + b_fx   (M=16384, N=1024)
  gemm3<<<256, 512, 0, stream>>>(Gx, Grb, Glb, WFT, F, b_fx, 1024, nullptr,
                                 nullptr);
  // IOU = [Xb|HR|HL] @ WIOUT^T + b_ioux, compacted rows (N=3072)
  gemm3<<<768, 512, 0, stream>>>(Xb, HRb, HLb, WIOUT, IOU, b_ioux, 3072,
                                 rowidx, mc);
  epi_kernel<<<dim3(512, 32), 256, 0, stream>>>(IOU, F, h0, c0, idd, outh,
                                                outc);
}

// Round 11
// 541.236 us; speedup vs baseline: 1.2264x; 1.0617x over previous
//
#include <hip/hip_runtime.h>
#include <hip/hip_bf16.h>

typedef unsigned short u16;
typedef unsigned int u32;
typedef unsigned long long u64;
typedef float f32x4 __attribute__((ext_vector_type(4)));
typedef u16 u16x4 __attribute__((ext_vector_type(4)));
typedef u16 u16x8 __attribute__((ext_vector_type(8)));
typedef short s16x8 __attribute__((ext_vector_type(8)));

// ---------- helpers ----------
__device__ __forceinline__ u16 f2b(float f) {
  return __builtin_bit_cast(u16, __float2bfloat16(f));
}
__device__ __forceinline__ float b2f(u16 u) {
  return __builtin_bit_cast(float, ((u32)u) << 16);
}
__device__ __forceinline__ f32x4 ldb4(const u16* __restrict__ p) {
  u16x4 v = *(const u16x4*)p;
  f32x4 r;
#pragma unroll
  for (int i = 0; i < 4; ++i) r[i] = b2f(v[i]);
  return r;
}
__device__ __forceinline__ u16x4 cvt4(f32x4 v) {
  u16x4 r;
#pragma unroll
  for (int i = 0; i < 4; ++i) r[i] = f2b(v[i]);
  return r;
}
__device__ __forceinline__ f32x4 sigm4(f32x4 x) {
  f32x4 r;
#pragma unroll
  for (int i = 0; i < 4; ++i) r[i] = 1.0f / (1.0f + __expf(-x[i]));
  return r;
}
__device__ __forceinline__ f32x4 tanh4(f32x4 x) {
  f32x4 r;
#pragma unroll
  for (int i = 0; i < 4; ++i) {
    float xx = fminf(fmaxf(x[i], -15.0f), 15.0f);
    float e = __expf(2.0f * xx);
    r[i] = (e - 1.0f) / (e + 1.0f);
  }
  return r;
}

__device__ __forceinline__ void gload_lds16(const void* g, void* l) {
  typedef __attribute__((address_space(1))) const u32 gq_t;
  typedef __attribute__((address_space(3))) u32 lq_t;
  gq_t* gp = (gq_t*)(u64)(size_t)g;
  lq_t* lp = (lq_t*)(u32)(size_t)l;
  __builtin_amdgcn_global_load_lds(gp, lp, 16, 0, 0);
}

__device__ __forceinline__ f32x4 mfma_b(u16x8 a, u16x8 b, f32x4 c) {
  return __builtin_amdgcn_mfma_f32_16x16x32_bf16(
      __builtin_bit_cast(s16x8, a), __builtin_bit_cast(s16x8, b), c, 0, 0, 0);
}

// ---------- kernel 1: prep ----------
// One block per (j=node, b=batch). Writes interleaved rows:
//   XHH[grow][3072] = [bf16(x[grow]) | HR | HL]   (HR/HL = scatter-aggregates)
//   AF [grow][3072] = [bf16(x[d])    | bf16(h0[dr]) | bf16(h0[dl])]
// plus the updated flag.
__global__ __launch_bounds__(256) void prep_kernel(
    const float* __restrict__ x, const float* __restrict__ h0,
    const int* __restrict__ idd, const int* __restrict__ idr,
    const int* __restrict__ idl, u16* __restrict__ XHH, u16* __restrict__ AF,
    int* __restrict__ updated) {
  __shared__ int listR[512], listL[512];
  __shared__ int cnt[3];
  const int j = blockIdx.x;
  const int b = blockIdx.y;
  const int tid = threadIdx.x;
  const int lane = tid & 63;
  const int wave = tid >> 6;

  if (wave < 3) {
    const int* ids = (wave == 0 ? idd : (wave == 1 ? idr : idl)) + (size_t)b * 512;
    int* lst = (wave == 1 ? listR : listL);
    int base = 0;
#pragma unroll
    for (int c2 = 0; c2 < 8; ++c2) {
      int l = c2 * 64 + lane;
      int id = ids[l];
      u64 m = __ballot(id == j);
      if (wave > 0 && id == j) {
        int pos = __popcll(m & ((1ull << lane) - 1ull));
        lst[base + pos] = l;
      }
      base += __popcll(m);
    }
    if (lane == 0) cnt[wave] = base;
  }
  __syncthreads();

  const size_t grow = (size_t)b * 512 + j;
  if (tid == 0) updated[grow] = (cnt[0] > 0 && j != 0) ? 1 : 0;

  const int k = tid * 4;
  const size_t bbase = (size_t)b * 512;
  u16* xr = XHH + grow * 3072;
  u16* ar = AF + grow * 3072;

  *(u16x4*)(xr + k) = cvt4(*(const f32x4*)(x + grow * 1024 + k));

  f32x4 sr = {0.f, 0.f, 0.f, 0.f};
  for (int t = 0; t < cnt[1]; ++t)
    sr += *(const f32x4*)(h0 + (bbase + listR[t]) * 1024 + k);
  *(u16x4*)(xr + 1024 + k) = cvt4(sr);

  f32x4 sl = {0.f, 0.f, 0.f, 0.f};
  for (int t = 0; t < cnt[2]; ++t)
    sl += *(const f32x4*)(h0 + (bbase + listL[t]) * 1024 + k);
  *(u16x4*)(xr + 2048 + k) = cvt4(sl);

  const int dd = idd[grow], rr = idr[grow], ll = idl[grow];
  *(u16x4*)(ar + k) = cvt4(*(const f32x4*)(x + (bbase + dd) * 1024 + k));
  *(u16x4*)(ar + 1024 + k) = cvt4(*(const f32x4*)(h0 + (bbase + rr) * 1024 + k));
  *(u16x4*)(ar + 2048 + k) = cvt4(*(const f32x4*)(h0 + (bbase + ll) * 1024 + k));
}

// ---------- kernel 2: compact — rowidx, cidx, mc (single block) ----------
__global__ __launch_bounds__(1024) void compact_kernel(
    const int* __restrict__ updated, int* __restrict__ rowidx,
    int* __restrict__ cidx, int* __restrict__ mc) {
  __shared__ int sc[1024];
  const int t = threadIdx.x;
  int fl[16];
  int cl = 0;
#pragma unroll
  for (int i = 0; i < 16; ++i) {
    fl[i] = updated[t * 16 + i];
    cl += fl[i];
  }
  sc[t] = cl;
  __syncthreads();
  for (int d = 1; d < 1024; d <<= 1) {
    int v = sc[t];
    int add = (t >= d) ? sc[t - d] : 0;
    __syncthreads();
    sc[t] = v + add;
    __syncthreads();
  }
  const int Mc = sc[1023];
  int pos = sc[t] - cl;  // exclusive prefix
#pragma unroll
  for (int i = 0; i < 16; ++i)
    if (fl[i]) {
      rowidx[pos] = t * 16 + i;
      cidx[t * 16 + i] = pos;
      ++pos;
    }
  for (int s = Mc + t; s < 16384; s += 1024) rowidx[s] = 0;
  if (t == 0) mc[0] = Mc;
}

// ---------- kernel 3: gather Ac[i] = XHH[rowidx[i]] for i < McPad ----------
__global__ __launch_bounds__(256) void gather_kernel(
    const u16* __restrict__ XHH, const int* __restrict__ rowidx,
    const int* __restrict__ mc, u16* __restrict__ Ac) {
  const int McPad = (mc[0] + 255) & ~255;
  const int total = McPad * 384;  // 16B units per row = 3072*2/16
  for (int u = blockIdx.x * 256 + threadIdx.x; u < total;
       u += gridDim.x * 256) {
    const int row = u / 384;
    const int c16 = u - row * 384;
    *(u16x8*)(Ac + (size_t)row * 3072 + c16 * 8) =
        *(const u16x8*)(XHH + (size_t)rowidx[row] * 3072 + c16 * 8);
  }
}

// ---------- kernel 4: pack weights: WIOUT[3072][3072], WFT[1024][3072] -----
__global__ __launch_bounds__(256) void packw_kernel(
    const float* __restrict__ W_ioux, const float* __restrict__ W_iouh_r,
    const float* __restrict__ W_iouh_l, const float* __restrict__ W_fx,
    const float* __restrict__ W_fh0, const float* __restrict__ W_fh1,
    const float* __restrict__ W_fh2, const float* __restrict__ W_fh3,
    u16* __restrict__ WIOUT, u16* __restrict__ WFT) {
  const int t = blockIdx.x * 256 + threadIdx.x;
  const int NIOU = 3072 * 384;
  float v[8];
  if (t < NIOU) {
    const int n = t % 3072;
    const int k0 = (t / 3072) * 8;
    if (k0 < 1024) {
#pragma unroll
      for (int i = 0; i < 8; ++i) v[i] = W_ioux[(size_t)(k0 + i) * 3072 + n];
    } else if (k0 < 2048) {
#pragma unroll
      for (int i = 0; i < 8; ++i) v[i] = W_iouh_r[(size_t)(k0 - 1024 + i) * 3072 + n];
    } else {
#pragma unroll
      for (int i = 0; i < 8; ++i) v[i] = W_iouh_l[(size_t)(k0 - 2048 + i) * 3072 + n];
    }
    u16x8 o;
#pragma unroll
    for (int i = 0; i < 8; ++i) o[i] = f2b(v[i]);
    *(u16x8*)(WIOUT + (size_t)n * 3072 + k0) = o;
  } else {
    const int u = t - NIOU;
    const int n = u & 1023;
    const int k0 = (u >> 10) * 8;
    if (k0 < 1024) {
#pragma unroll
      for (int i = 0; i < 8; ++i) v[i] = W_fx[(size_t)(k0 + i) * 1024 + n];
    } else if (k0 < 2048) {
#pragma unroll
      for (int i = 0; i < 8; ++i)
        v[i] = W_fh0[(size_t)(k0 - 1024 + i) * 1024 + n] +
               W_fh1[(size_t)(k0 - 1024 + i) * 1024 + n];
    } else {
#pragma unroll
      for (int i = 0; i < 8; ++i)
        v[i] = W_fh2[(size_t)(k0 - 2048 + i) * 1024 + n] +
               W_fh3[(size_t)(k0 - 2048 + i) * 1024 + n];
    }
    u16x8 o;
#pragma unroll
    for (int i = 0; i < 8; ++i) o[i] = f2b(v[i]);
    *(u16x8*)(WFT + (size_t)n * 3072 + k0) = o;
  }
}

// ---------- kernel 5: merged 256x256 NT GEMM (R9 champion schedule) --------
// Grid 1024: bid<256 -> F role (AF @ WFT^T + b_fx -> F, N=1024);
// else IOU role (Ac @ WIOUT^T + b_ioux -> IOUc compact rows, N=3072,
// early-exit past McPad). A and B strides are 3072 for both -> one code path.
#define BARRIER __builtin_amdgcn_s_barrier()
#define VMCNT(n) asm volatile("s_waitcnt vmcnt(" #n ")")

__global__ __launch_bounds__(512, 2) void gemm_m(
    const u16* __restrict__ AF, const u16* __restrict__ WFT,
    u16* __restrict__ F, const float* __restrict__ bfx,
    const u16* __restrict__ Ac, const u16* __restrict__ WIOUT,
    u16* __restrict__ IOUc, const float* __restrict__ biou,
    const int* __restrict__ mc) {
  const int nk = 48;  // K = 3072
  __shared__ u16 lds_u16[65536];  // 128 KB: A 2x32KB @0, B 2x32KB @65536
  char* ldsb = (char*)lds_u16;
  const int tid = threadIdx.x;
  const int lane = tid & 63;
  const int wave = tid >> 6;
  const int wm = wave >> 2, wn = wave & 3;

  const int bid = blockIdx.x;
  const bool isF = bid < 256;
  const int lb = isF ? bid : bid - 256;
  const int nwg = isF ? 256 : 768;
  const int nbn = isF ? 4 : 12;
  const int swz = (lb & 7) * (nwg >> 3) + (lb >> 3);
  const int bm = swz / nbn, bn = swz % nbn;

  if (!isF) {
    const int McPad = (mc[0] + 255) & ~255;
    if (bm * 256 >= McPad) return;
  }

  const int N = isF ? 1024 : 3072;
  const u16* Abase = isF ? AF : Ac;
  const u16* Bt = isF ? WFT : WIOUT;
  u16* C = isF ? F : IOUc;
  const float* bias = isF ? bfx : biou;

  // staging source: inverse-XOR-swizzled so swizzled ds_reads see linear data
  const int srow = tid >> 3;
  const int ssw = (((tid & 7) * 16) ^ ((srow & 7) << 4)) >> 1;
  const u16* Ab = Abase + (size_t)(bm * 256 + srow) * 3072 + ssw;
  const u16* Bb = Bt + (size_t)(bn * 256 + srow) * 3072 + ssw;

#define SAg(PB, c, kt)                                                \
  gload_lds16(Ab + (size_t)(c) * 64 * 3072 + (size_t)(kt) * 64,       \
              ldsb + (PB) + (c) * 8192 + tid * 16)
#define SBg(PB, c, kt)                                                \
  gload_lds16(Bb + (size_t)(c) * 64 * 3072 + (size_t)(kt) * 64,       \
              ldsb + 65536 + (PB) + (c) * 8192 + tid * 16)

  // fragment read offsets (XOR swizzle depends only on lane)
  const int lb15 = lane & 15;
  const int lh16 = (lane >> 4) * 16;
  const int sw = (lane & 7) << 4;
  int a_off[2], b_off[2];
  a_off[0] = (wm * 64 + lb15) * 128 + (lh16 ^ sw);
  a_off[1] = (wm * 64 + lb15) * 128 + ((64 + lh16) ^ sw);
  b_off[0] = 65536 + (wn * 32 + lb15) * 128 + (lh16 ^ sw);
  b_off[1] = 65536 + (wn * 32 + lb15) * 128 + ((64 + lh16) ^ sw);

#define LDA(AR, PB, MS)                                                    \
  _Pragma("unroll") for (int fm = 0; fm < 4; ++fm) _Pragma("unroll")       \
      for (int kk = 0; kk < 2; ++kk) AR[fm][kk] =                          \
          *(const u16x8*)(ldsb + (PB) + a_off[kk] + (MS)*16384 + fm * 2048)
#define LDB(BR, PB, NS)                                                    \
  _Pragma("unroll") for (int fn = 0; fn < 2; ++fn) _Pragma("unroll")       \
      for (int kk = 0; kk < 2; ++kk) BR[fn][kk] =                          \
          *(const u16x8*)(ldsb + (PB) + b_off[kk] + (NS)*16384 + fn * 2048)
#define MFMAQ(MS, NS, AR, BR)                                              \
  _Pragma("unroll") for (int kk = 0; kk < 2; ++kk) _Pragma("unroll")       \
      for (int fm = 0; fm < 4; ++fm) _Pragma("unroll")                     \
      for (int fn = 0; fn < 2; ++fn) acc[MS][fm][NS][fn] =                 \
          mfma_b(AR[fm][kk], BR[fn][kk], acc[MS][fm][NS][fn])

  u16x8 ar0[4][2], ar1[4][2], br0[2][2], br1[2][2];
  f32x4 acc[2][4][2][2] = {};

  // prologue: tile0 all 8 chunks -> buf0; tile1's A01,B23 -> buf1
  SAg(0, 0, 0); SAg(0, 1, 0); SAg(0, 2, 0); SAg(0, 3, 0);
  SBg(0, 0, 0); SBg(0, 1, 0); SBg(0, 2, 0); SBg(0, 3, 0);
  SAg(32768, 0, 1); SAg(32768, 1, 1);
  SBg(32768, 2, 1); SBg(32768, 3, 1);
  VMCNT(4);
  BARRIER;

#define TILEBODY(PB, QB, Tcur)                                          \
  {                                                                     \
    const int s1 = ((Tcur) + 1 < nk) ? (Tcur) + 1 : nk - 1;             \
    const int s2 = ((Tcur) + 2 < nk) ? (Tcur) + 2 : nk - 1;             \
    SAg(QB, 2, s1); SAg(QB, 3, s1);                                     \
    LDB(br0, PB, 0);                                                    \
    LDA(ar0, PB, 0);                                                    \
    __builtin_amdgcn_s_setprio(1);                                      \
    MFMAQ(0, 0, ar0, br0);                                              \
    __builtin_amdgcn_s_setprio(0);                                      \
    BARRIER;                                                            \
    SBg(QB, 0, s1); SBg(QB, 1, s1);                                     \
    LDB(br1, PB, 1);                                                    \
    __builtin_amdgcn_s_setprio(1);                                      \
    MFMAQ(0, 1, ar0, br1);                                              \
    __builtin_amdgcn_s_setprio(0);                                      \
    BARRIER;                                                            \
    SAg(PB, 0, s2); SAg(PB, 1, s2);                                     \
    LDA(ar1, PB, 1);                                                    \
    __builtin_amdgcn_s_setprio(1);                                      \
    MFMAQ(1, 1, ar1, br1);                                              \
    __builtin_amdgcn_s_setprio(0);                                      \
    BARRIER;                                                            \
    SBg(PB, 2, s2); SBg(PB, 3, s2);                                     \
    __builtin_amdgcn_s_setprio(1);                                      \
    MFMAQ(1, 0, ar1, br0);                                              \
    __builtin_amdgcn_s_setprio(0);                                      \
    VMCNT(4);                                                           \
    BARRIER;                                                            \
  }

  for (int T = 0; T < nk; T += 2) {
    TILEBODY(0, 32768, T);
    TILEBODY(32768, 0, T + 1);
  }
  VMCNT(0);

  // epilogue
#pragma unroll
  for (int ms = 0; ms < 2; ++ms)
#pragma unroll
    for (int fm = 0; fm < 4; ++fm) {
      const int row0 = bm * 256 + ms * 128 + wm * 64 + fm * 16 + ((lane >> 4) * 4);
#pragma unroll
      for (int ns = 0; ns < 2; ++ns)
#pragma unroll
        for (int fn = 0; fn < 2; ++fn) {
          const int col = bn * 256 + ns * 128 + wn * 32 + fn * 16 + lb15;
          const float bv = bias[col];
#pragma unroll
          for (int r = 0; r < 4; ++r)
            C[(size_t)(row0 + r) * N + col] = f2b(acc[ms][fm][ns][fn][r] + bv);
        }
    }
#undef SAg
#undef SBg
#undef LDA
#undef LDB
#undef MFMAQ
#undef TILEBODY
}

// ---------- kernel 6: epilogue — gates + fc scatter (D-list only) ----------
__global__ __launch_bounds__(256) void epi_kernel(
    const u16* __restrict__ IOUc, const u16* __restrict__ F,
    const float* __restrict__ h0, const float* __restrict__ c0,
    const int* __restrict__ idd, const int* __restrict__ cidx,
    float* __restrict__ outh, float* __restrict__ outc) {
  __shared__ int listD[512];
  __shared__ int cnt0;
  const int j = blockIdx.x;
  const int b = blockIdx.y;
  const int tid = threadIdx.x;
  const int lane = tid & 63;
  const int wave = tid >> 6;

  if (wave == 0) {
    const int* ids = idd + (size_t)b * 512;
    int base = 0;
#pragma unroll
    for (int c2 = 0; c2 < 8; ++c2) {
      int l = c2 * 64 + lane;
      int id = ids[l];
      u64 m = __ballot(id == j);
      if (id == j) {
        int pos = __popcll(m & ((1ull << lane) - 1ull));
        listD[base + pos] = l;
      }
      base += __popcll(m);
    }
    if (lane == 0) cnt0 = base;
  }
  __syncthreads();

  const int nD = cnt0;
  const size_t grow = (size_t)b * 512 + j;
  const int k = tid * 4;

  if (!((nD > 0) && (j != 0))) {  // not updated: pass through
    f32x4 hv = *(const f32x4*)(h0 + grow * 1024 + k);
    f32x4 cv = *(const f32x4*)(c0 + grow * 1024 + k);
    *(f32x4*)(outh + grow * 1024 + k) = hv;
    *(f32x4*)(outc + grow * 1024 + k) = cv;
    return;
  }

  const u16* io = IOUc + (size_t)cidx[grow] * 3072;
  f32x4 gi = sigm4(ldb4(io + k));
  f32x4 go = sigm4(ldb4(io + 1024 + k));
  f32x4 gu = tanh4(ldb4(io + 2048 + k));
  f32x4 c = gi * gu;
  for (int t = 0; t < nD; ++t) {
    const size_t crow = (size_t)b * 512 + listD[t];
    f32x4 fg = sigm4(ldb4(F + crow * 1024 + k));  // b_fx folded in GEMM
    f32x4 cc = *(const f32x4*)(c0 + crow * 1024 + k);
    c += fg * cc;
  }
  f32x4 h = go * tanh4(c);
  *(f32x4*)(outh + grow * 1024 + k) = h;
  *(f32x4*)(outc + grow * 1024 + k) = c;
}

// ---------- host ----------
extern "C" void kernel_launch(void* const* d_in, const int* in_sizes, int n_in,
                              void* d_out, int out_size, void* d_ws,
                              size_t ws_size, hipStream_t stream) {
  const float* x = (const float*)d_in[0];
  const float* h0 = (const float*)d_in[1];
  const float* c0 = (const float*)d_in[2];
  const float* W_ioux = (const float*)d_in[3];
  const float* b_ioux = (const float*)d_in[4];
  const float* W_iouh_r = (const float*)d_in[5];
  const float* W_iouh_l = (const float*)d_in[6];
  const float* W_fx = (const float*)d_in[7];
  const float* b_fx = (const float*)d_in[8];
  const float* W_fh0 = (const float*)d_in[9];
  const float* W_fh1 = (const float*)d_in[10];
  const float* W_fh2 = (const float*)d_in[11];
  const float* W_fh3 = (const float*)d_in[12];
  const int* idd = (const int*)d_in[13];
  const int* idr = (const int*)d_in[14];
  const int* idl = (const int*)d_in[15];

  const size_t M = 16384;  // B*L
  char* p = (char*)d_ws;
  u16* XHH = (u16*)p;   p += M * 3072 * 2;  // 96MB (reused as IOUc)
  u16* AF = (u16*)p;    p += M * 3072 * 2;  // 96MB
  u16* Ac = (u16*)p;    p += M * 3072 * 2;  // 96MB
  u16* WIOUT = (u16*)p; p += (size_t)3072 * 3072 * 2;  // 18MB
  u16* WFT = (u16*)p;   p += (size_t)1024 * 3072 * 2;  // 6MB
  u16* F = (u16*)p;     p += M * 1024 * 2;  // 32MB
  int* updated = (int*)p; p += M * 4;
  int* rowidx = (int*)p;  p += M * 4;
  int* cidx = (int*)p;    p += M * 4;
  int* mc = (int*)p;      p += 64;
  u16* IOUc = XHH;  // alias: XHH dead after gather_kernel

  float* outh = (float*)d_out;
  float* outc = outh + M * 1024;

  prep_kernel<<<dim3(512, 32), 256, 0, stream>>>(x, h0, idd, idr, idl, XHH,
                                                 AF, updated);
  compact_kernel<<<1, 1024, 0, stream>>>(updated, rowidx, cidx, mc);
  gather_kernel<<<2048, 256, 0, stream>>>(XHH, rowidx, mc, Ac);
  packw_kernel<<<6144, 256, 0, stream>>>(W_ioux, W_iouh_r, W_iouh_l, W_fx,
                                         W_fh0, W_fh1, W_fh2, W_fh3, WIOUT,
                                         WFT);
  gemm_m<<<1024, 512, 0, stream>>>(AF, WFT, F, b_fx, Ac, WIOUT, IOUc, b_ioux,
                                   mc);
  epi_kernel<<<dim3(512, 32), 256, 0, stream>>>(IOUc, F, h0, c0, idd, cidx,
                                                outh, outc);
}

// Round 12
// 491.518 us; speedup vs baseline: 1.3505x; 1.1012x over previous
//
#include <hip/hip_runtime.h>
#include <hip/hip_bf16.h>

typedef unsigned short u16;
typedef unsigned int u32;
typedef unsigned long long u64;
typedef float f32x4 __attribute__((ext_vector_type(4)));
typedef u16 u16x4 __attribute__((ext_vector_type(4)));
typedef u16 u16x8 __attribute__((ext_vector_type(8)));
typedef short s16x8 __attribute__((ext_vector_type(8)));

// ---------- helpers ----------
__device__ __forceinline__ u16 f2b(float f) {
  return __builtin_bit_cast(u16, __float2bfloat16(f));
}
__device__ __forceinline__ float b2f(u16 u) {
  return __builtin_bit_cast(float, ((u32)u) << 16);
}
__device__ __forceinline__ f32x4 ldb4(const u16* __restrict__ p) {
  u16x4 v = *(const u16x4*)p;
  f32x4 r;
#pragma unroll
  for (int i = 0; i < 4; ++i) r[i] = b2f(v[i]);
  return r;
}
__device__ __forceinline__ u16x4 cvt4(f32x4 v) {
  u16x4 r;
#pragma unroll
  for (int i = 0; i < 4; ++i) r[i] = f2b(v[i]);
  return r;
}
__device__ __forceinline__ f32x4 sigm4(f32x4 x) {
  f32x4 r;
#pragma unroll
  for (int i = 0; i < 4; ++i) r[i] = 1.0f / (1.0f + __expf(-x[i]));
  return r;
}
__device__ __forceinline__ f32x4 tanh4(f32x4 x) {
  f32x4 r;
#pragma unroll
  for (int i = 0; i < 4; ++i) {
    float xx = fminf(fmaxf(x[i], -15.0f), 15.0f);
    float e = __expf(2.0f * xx);
    r[i] = (e - 1.0f) / (e + 1.0f);
  }
  return r;
}

__device__ __forceinline__ void gload_lds16(const void* g, void* l) {
  typedef __attribute__((address_space(1))) const u32 gq_t;
  typedef __attribute__((address_space(3))) u32 lq_t;
  gq_t* gp = (gq_t*)(u64)(size_t)g;
  lq_t* lp = (lq_t*)(u32)(size_t)l;
  __builtin_amdgcn_global_load_lds(gp, lp, 16, 0, 0);
}

__device__ __forceinline__ f32x4 mfma_b(u16x8 a, u16x8 b, f32x4 c) {
  return __builtin_amdgcn_mfma_f32_16x16x32_bf16(
      __builtin_bit_cast(s16x8, a), __builtin_bit_cast(s16x8, b), c, 0, 0, 0);
}

// ---------- kernel 1: flags — updated[j] = (exists l: idd[l]==j) && j!=0 ----
__global__ __launch_bounds__(512) void flags_kernel(
    const int* __restrict__ idd, int* __restrict__ updated) {
  __shared__ int sf[512];
  const int b = blockIdx.x;
  const int l = threadIdx.x;
  sf[l] = 0;
  __syncthreads();
  const int id = idd[(size_t)b * 512 + l];
  sf[id] = 1;  // benign same-value race
  __syncthreads();
  updated[(size_t)b * 512 + l] = (l != 0) ? sf[l] : 0;
}

// ---------- kernel 2: compact — cidx (compact index per updated row), mc ---
__global__ __launch_bounds__(1024) void compact_kernel(
    const int* __restrict__ updated, int* __restrict__ cidx,
    int* __restrict__ mc) {
  __shared__ int sc[1024];
  const int t = threadIdx.x;
  int fl[16];
  int cl = 0;
#pragma unroll
  for (int i = 0; i < 16; ++i) {
    fl[i] = updated[t * 16 + i];
    cl += fl[i];
  }
  sc[t] = cl;
  __syncthreads();
  for (int d = 1; d < 1024; d <<= 1) {
    int v = sc[t];
    int add = (t >= d) ? sc[t - d] : 0;
    __syncthreads();
    sc[t] = v + add;
    __syncthreads();
  }
  int pos = sc[t] - cl;  // exclusive prefix
#pragma unroll
  for (int i = 0; i < 16; ++i)
    if (fl[i]) cidx[t * 16 + i] = pos++;
  if (t == 1023) mc[0] = sc[1023];
}

// ---------- kernel 3: prep ----------
// Always: AF[grow][3072] = [bf16(x[d]) | bf16(h0[dr]) | bf16(h0[dl])].
// If updated: Ac[cidx[grow]][3072] = [bf16(x[grow]) | HR | HL] (compacted),
// where HR/HL are the dr/dl scatter-aggregates of h0 rows.
__global__ __launch_bounds__(256) void prep_kernel(
    const float* __restrict__ x, const float* __restrict__ h0,
    const int* __restrict__ idd, const int* __restrict__ idr,
    const int* __restrict__ idl, const int* __restrict__ updated,
    const int* __restrict__ cidx, u16* __restrict__ AF, u16* __restrict__ Ac) {
  __shared__ int listR[512], listL[512];
  __shared__ int cnt[2];
  const int j = blockIdx.x;
  const int b = blockIdx.y;
  const int tid = threadIdx.x;
  const int lane = tid & 63;
  const int wave = tid >> 6;
  const size_t grow = (size_t)b * 512 + j;
  const size_t bbase = (size_t)b * 512;
  const int k = tid * 4;

  // AF gather (every row)
  const int dd = idd[grow], rr = idr[grow], ll = idl[grow];
  u16* ar = AF + grow * 3072;
  *(u16x4*)(ar + k) = cvt4(*(const f32x4*)(x + (bbase + dd) * 1024 + k));
  *(u16x4*)(ar + 1024 + k) =
      cvt4(*(const f32x4*)(h0 + (bbase + rr) * 1024 + k));
  *(u16x4*)(ar + 2048 + k) =
      cvt4(*(const f32x4*)(h0 + (bbase + ll) * 1024 + k));

  if (!updated[grow]) return;  // block-uniform

  if (wave == 1 || wave == 2) {
    const int* ids = (wave == 1 ? idr : idl) + bbase;
    int* lst = (wave == 1 ? listR : listL);
    int base = 0;
#pragma unroll
    for (int c2 = 0; c2 < 8; ++c2) {
      int l = c2 * 64 + lane;
      int id = ids[l];
      u64 m = __ballot(id == j);
      if (id == j) {
        int pos = __popcll(m & ((1ull << lane) - 1ull));
        lst[base + pos] = l;
      }
      base += __popcll(m);
    }
    if (lane == 0) cnt[wave - 1] = base;
  }
  __syncthreads();

  u16* cr = Ac + (size_t)cidx[grow] * 3072;
  *(u16x4*)(cr + k) = cvt4(*(const f32x4*)(x + grow * 1024 + k));

  f32x4 sr = {0.f, 0.f, 0.f, 0.f};
  for (int t = 0; t < cnt[0]; ++t)
    sr += *(const f32x4*)(h0 + (bbase + listR[t]) * 1024 + k);
  *(u16x4*)(cr + 1024 + k) = cvt4(sr);

  f32x4 sl = {0.f, 0.f, 0.f, 0.f};
  for (int t = 0; t < cnt[1]; ++t)
    sl += *(const f32x4*)(h0 + (bbase + listL[t]) * 1024 + k);
  *(u16x4*)(cr + 2048 + k) = cvt4(sl);
}

// ---------- kernel 4: pack weights: WIOUT[3072][3072], WFT[1024][3072] -----
__global__ __launch_bounds__(256) void packw_kernel(
    const float* __restrict__ W_ioux, const float* __restrict__ W_iouh_r,
    const float* __restrict__ W_iouh_l, const float* __restrict__ W_fx,
    const float* __restrict__ W_fh0, const float* __restrict__ W_fh1,
    const float* __restrict__ W_fh2, const float* __restrict__ W_fh3,
    u16* __restrict__ WIOUT, u16* __restrict__ WFT) {
  const int t = blockIdx.x * 256 + threadIdx.x;
  const int NIOU = 3072 * 384;
  float v[8];
  if (t < NIOU) {
    const int n = t % 3072;
    const int k0 = (t / 3072) * 8;
    if (k0 < 1024) {
#pragma unroll
      for (int i = 0; i < 8; ++i) v[i] = W_ioux[(size_t)(k0 + i) * 3072 + n];
    } else if (k0 < 2048) {
#pragma unroll
      for (int i = 0; i < 8; ++i) v[i] = W_iouh_r[(size_t)(k0 - 1024 + i) * 3072 + n];
    } else {
#pragma unroll
      for (int i = 0; i < 8; ++i) v[i] = W_iouh_l[(size_t)(k0 - 2048 + i) * 3072 + n];
    }
    u16x8 o;
#pragma unroll
    for (int i = 0; i < 8; ++i) o[i] = f2b(v[i]);
    *(u16x8*)(WIOUT + (size_t)n * 3072 + k0) = o;
  } else {
    const int u = t - NIOU;
    const int n = u & 1023;
    const int k0 = (u >> 10) * 8;
    if (k0 < 1024) {
#pragma unroll
      for (int i = 0; i < 8; ++i) v[i] = W_fx[(size_t)(k0 + i) * 1024 + n];
    } else if (k0 < 2048) {
#pragma unroll
      for (int i = 0; i < 8; ++i)
        v[i] = W_fh0[(size_t)(k0 - 1024 + i) * 1024 + n] +
               W_fh1[(size_t)(k0 - 1024 + i) * 1024 + n];
    } else {
#pragma unroll
      for (int i = 0; i < 8; ++i)
        v[i] = W_fh2[(size_t)(k0 - 2048 + i) * 1024 + n] +
               W_fh3[(size_t)(k0 - 2048 + i) * 1024 + n];
    }
    u16x8 o;
#pragma unroll
    for (int i = 0; i < 8; ++i) o[i] = f2b(v[i]);
    *(u16x8*)(WFT + (size_t)n * 3072 + k0) = o;
  }
}

// ---------- kernel 5: merged 256x256 NT GEMM (R9 champion schedule) --------
// Grid 1024: bid<256 -> F role (AF @ WFT^T + b_fx -> F, N=1024);
// else IOU role (Ac @ WIOUT^T + b_ioux -> IOUc compact rows, N=3072,
// early-exit past McPad). A and B strides are 3072 for both -> one code path.
#define BARRIER __builtin_amdgcn_s_barrier()
#define VMCNT(n) asm volatile("s_waitcnt vmcnt(" #n ")")

__global__ __launch_bounds__(512, 2) void gemm_m(
    const u16* __restrict__ AF, const u16* __restrict__ WFT,
    u16* __restrict__ F, const float* __restrict__ bfx,
    const u16* __restrict__ Ac, const u16* __restrict__ WIOUT,
    u16* __restrict__ IOUc, const float* __restrict__ biou,
    const int* __restrict__ mc) {
  const int nk = 48;  // K = 3072
  __shared__ u16 lds_u16[65536];  // 128 KB: A 2x32KB @0, B 2x32KB @65536
  char* ldsb = (char*)lds_u16;
  const int tid = threadIdx.x;
  const int lane = tid & 63;
  const int wave = tid >> 6;
  const int wm = wave >> 2, wn = wave & 3;

  const int bid = blockIdx.x;
  const bool isF = bid < 256;
  const int lb = isF ? bid : bid - 256;
  const int nwg = isF ? 256 : 768;
  const int nbn = isF ? 4 : 12;
  const int swz = (lb & 7) * (nwg >> 3) + (lb >> 3);
  const int bm = swz / nbn, bn = swz % nbn;

  if (!isF) {
    const int McPad = (mc[0] + 255) & ~255;
    if (bm * 256 >= McPad) return;
  }

  const int N = isF ? 1024 : 3072;
  const u16* Abase = isF ? AF : Ac;
  const u16* Bt = isF ? WFT : WIOUT;
  u16* C = isF ? F : IOUc;
  const float* bias = isF ? bfx : biou;

  // staging source: inverse-XOR-swizzled so swizzled ds_reads see linear data
  const int srow = tid >> 3;
  const int ssw = (((tid & 7) * 16) ^ ((srow & 7) << 4)) >> 1;
  const u16* Ab = Abase + (size_t)(bm * 256 + srow) * 3072 + ssw;
  const u16* Bb = Bt + (size_t)(bn * 256 + srow) * 3072 + ssw;

#define SAg(PB, c, kt)                                                \
  gload_lds16(Ab + (size_t)(c) * 64 * 3072 + (size_t)(kt) * 64,       \
              ldsb + (PB) + (c) * 8192 + tid * 16)
#define SBg(PB, c, kt)                                                \
  gload_lds16(Bb + (size_t)(c) * 64 * 3072 + (size_t)(kt) * 64,       \
              ldsb + 65536 + (PB) + (c) * 8192 + tid * 16)

  // fragment read offsets (XOR swizzle depends only on lane)
  const int lb15 = lane & 15;
  const int lh16 = (lane >> 4) * 16;
  const int sw = (lane & 7) << 4;
  int a_off[2], b_off[2];
  a_off[0] = (wm * 64 + lb15) * 128 + (lh16 ^ sw);
  a_off[1] = (wm * 64 + lb15) * 128 + ((64 + lh16) ^ sw);
  b_off[0] = 65536 + (wn * 32 + lb15) * 128 + (lh16 ^ sw);
  b_off[1] = 65536 + (wn * 32 + lb15) * 128 + ((64 + lh16) ^ sw);

#define LDA(AR, PB, MS)                                                    \
  _Pragma("unroll") for (int fm = 0; fm < 4; ++fm) _Pragma("unroll")       \
      for (int kk = 0; kk < 2; ++kk) AR[fm][kk] =                          \
          *(const u16x8*)(ldsb + (PB) + a_off[kk] + (MS)*16384 + fm * 2048)
#define LDB(BR, PB, NS)                                                    \
  _Pragma("unroll") for (int fn = 0; fn < 2; ++fn) _Pragma("unroll")       \
      for (int kk = 0; kk < 2; ++kk) BR[fn][kk] =                          \
          *(const u16x8*)(ldsb + (PB) + b_off[kk] + (NS)*16384 + fn * 2048)
#define MFMAQ(MS, NS, AR, BR)                                              \
  _Pragma("unroll") for (int kk = 0; kk < 2; ++kk) _Pragma("unroll")       \
      for (int fm = 0; fm < 4; ++fm) _Pragma("unroll")                     \
      for (int fn = 0; fn < 2; ++fn) acc[MS][fm][NS][fn] =                 \
          mfma_b(AR[fm][kk], BR[fn][kk], acc[MS][fm][NS][fn])

  u16x8 ar0[4][2], ar1[4][2], br0[2][2], br1[2][2];
  f32x4 acc[2][4][2][2] = {};

  // prologue: tile0 all 8 chunks -> buf0; tile1's A01,B23 -> buf1
  SAg(0, 0, 0); SAg(0, 1, 0); SAg(0, 2, 0); SAg(0, 3, 0);
  SBg(0, 0, 0); SBg(0, 1, 0); SBg(0, 2, 0); SBg(0, 3, 0);
  SAg(32768, 0, 1); SAg(32768, 1, 1);
  SBg(32768, 2, 1); SBg(32768, 3, 1);
  VMCNT(4);
  BARRIER;

#define TILEBODY(PB, QB, Tcur)                                          \
  {                                                                     \
    const int s1 = ((Tcur) + 1 < nk) ? (Tcur) + 1 : nk - 1;             \
    const int s2 = ((Tcur) + 2 < nk) ? (Tcur) + 2 : nk - 1;             \
    SAg(QB, 2, s1); SAg(QB, 3, s1);                                     \
    LDB(br0, PB, 0);                                                    \
    LDA(ar0, PB, 0);                                                    \
    __builtin_amdgcn_s_setprio(1);                                      \
    MFMAQ(0, 0, ar0, br0);                                              \
    __builtin_amdgcn_s_setprio(0);                                      \
    BARRIER;                                                            \
    SBg(QB, 0, s1); SBg(QB, 1, s1);                                     \
    LDB(br1, PB, 1);                                                    \
    __builtin_amdgcn_s_setprio(1);                                      \
    MFMAQ(0, 1, ar0, br1);                                              \
    __builtin_amdgcn_s_setprio(0);                                      \
    BARRIER;                                                            \
    SAg(PB, 0, s2); SAg(PB, 1, s2);                                     \
    LDA(ar1, PB, 1);                                                    \
    __builtin_amdgcn_s_setprio(1);                                      \
    MFMAQ(1, 1, ar1, br1);                                              \
    __builtin_amdgcn_s_setprio(0);                                      \
    BARRIER;                                                            \
    SBg(PB, 2, s2); SBg(PB, 3, s2);                                     \
    __builtin_amdgcn_s_setprio(1);                                      \
    MFMAQ(1, 0, ar1, br0);                                              \
    __builtin_amdgcn_s_setprio(0);                                      \
    VMCNT(4);                                                           \
    BARRIER;                                                            \
  }

  for (int T = 0; T < nk; T += 2) {
    TILEBODY(0, 32768, T);
    TILEBODY(32768, 0, T + 1);
  }
  VMCNT(0);

  // epilogue
#pragma unroll
  for (int ms = 0; ms < 2; ++ms)
#pragma unroll
    for (int fm = 0; fm < 4; ++fm) {
      const int row0 = bm * 256 + ms * 128 + wm * 64 + fm * 16 + ((lane >> 4) * 4);
#pragma unroll
      for (int ns = 0; ns < 2; ++ns)
#pragma unroll
        for (int fn = 0; fn < 2; ++fn) {
          const int col = bn * 256 + ns * 128 + wn * 32 + fn * 16 + lb15;
          const float bv = bias[col];
#pragma unroll
          for (int r = 0; r < 4; ++r)
            C[(size_t)(row0 + r) * N + col] = f2b(acc[ms][fm][ns][fn][r] + bv);
        }
    }
#undef SAg
#undef SBg
#undef LDA
#undef LDB
#undef MFMAQ
#undef TILEBODY
}

// ---------- kernel 6: epilogue — gates + fc scatter (D-list only) ----------
__global__ __launch_bounds__(256) void epi_kernel(
    const u16* __restrict__ IOUc, const u16* __restrict__ F,
    const float* __restrict__ h0, const float* __restrict__ c0,
    const int* __restrict__ idd, const int* __restrict__ cidx,
    float* __restrict__ outh, float* __restrict__ outc) {
  __shared__ int listD[512];
  __shared__ int cnt0;
  const int j = blockIdx.x;
  const int b = blockIdx.y;
  const int tid = threadIdx.x;
  const int lane = tid & 63;
  const int wave = tid >> 6;

  if (wave == 0) {
    const int* ids = idd + (size_t)b * 512;
    int base = 0;
#pragma unroll
    for (int c2 = 0; c2 < 8; ++c2) {
      int l = c2 * 64 + lane;
      int id = ids[l];
      u64 m = __ballot(id == j);
      if (id == j) {
        int pos = __popcll(m & ((1ull << lane) - 1ull));
        listD[base + pos] = l;
      }
      base += __popcll(m);
    }
    if (lane == 0) cnt0 = base;
  }
  __syncthreads();

  const int nD = cnt0;
  const size_t grow = (size_t)b * 512 + j;
  const int k = tid * 4;

  if (!((nD > 0) && (j != 0))) {  // not updated: pass through
    f32x4 hv = *(const f32x4*)(h0 + grow * 1024 + k);
    f32x4 cv = *(const f32x4*)(c0 + grow * 1024 + k);
    *(f32x4*)(outh + grow * 1024 + k) = hv;
    *(f32x4*)(outc + grow * 1024 + k) = cv;
    return;
  }

  const u16* io = IOUc + (size_t)cidx[grow] * 3072;
  f32x4 gi = sigm4(ldb4(io + k));
  f32x4 go = sigm4(ldb4(io + 1024 + k));
  f32x4 gu = tanh4(ldb4(io + 2048 + k));
  f32x4 c = gi * gu;
  for (int t = 0; t < nD; ++t) {
    const size_t crow = (size_t)b * 512 + listD[t];
    f32x4 fg = sigm4(ldb4(F + crow * 1024 + k));  // b_fx folded in GEMM
    f32x4 cc = *(const f32x4*)(c0 + crow * 1024 + k);
    c += fg * cc;
  }
  f32x4 h = go * tanh4(c);
  *(f32x4*)(outh + grow * 1024 + k) = h;
  *(f32x4*)(outc + grow * 1024 + k) = c;
}

// ---------- host ----------
extern "C" void kernel_launch(void* const* d_in, const int* in_sizes, int n_in,
                              void* d_out, int out_size, void* d_ws,
                              size_t ws_size, hipStream_t stream) {
  const float* x = (const float*)d_in[0];
  const float* h0 = (const float*)d_in[1];
  const float* c0 = (const float*)d_in[2];
  const float* W_ioux = (const float*)d_in[3];
  const float* b_ioux = (const float*)d_in[4];
  const float* W_iouh_r = (const float*)d_in[5];
  const float* W_iouh_l = (const float*)d_in[6];
  const float* W_fx = (const float*)d_in[7];
  const float* b_fx = (const float*)d_in[8];
  const float* W_fh0 = (const float*)d_in[9];
  const float* W_fh1 = (const float*)d_in[10];
  const float* W_fh2 = (const float*)d_in[11];
  const float* W_fh3 = (const float*)d_in[12];
  const int* idd = (const int*)d_in[13];
  const int* idr = (const int*)d_in[14];
  const int* idl = (const int*)d_in[15];

  const size_t M = 16384;  // B*L
  char* p = (char*)d_ws;
  u16* AF = (u16*)p;    p += M * 3072 * 2;            // 96MB
  u16* Ac = (u16*)p;    p += M * 3072 * 2;            // 96MB
  u16* IOUc = (u16*)p;  p += M * 3072 * 2;            // 96MB
  u16* WIOUT = (u16*)p; p += (size_t)3072 * 3072 * 2; // 18MB
  u16* WFT = (u16*)p;   p += (size_t)1024 * 3072 * 2; // 6MB
  u16* F = (u16*)p;     p += M * 1024 * 2;            // 32MB
  int* updated = (int*)p; p += M * 4;
  int* cidx = (int*)p;    p += M * 4;
  int* mc = (int*)p;      p += 64;

  float* outh = (float*)d_out;
  float* outc = outh + M * 1024;

  flags_kernel<<<32, 512, 0, stream>>>(idd, updated);
  compact_kernel<<<1, 1024, 0, stream>>>(updated, cidx, mc);
  prep_kernel<<<dim3(512, 32), 256, 0, stream>>>(x, h0, idd, idr, idl,
                                                 updated, cidx, AF, Ac);
  packw_kernel<<<6144, 256, 0, stream>>>(W_ioux, W_iouh_r, W_iouh_l, W_fx,
                                         W_fh0, W_fh1, W_fh2, W_fh3, WIOUT,
                                         WFT);
  gemm_m<<<1024, 512, 0, stream>>>(AF, WFT, F, b_fx, Ac, WIOUT, IOUc, b_ioux,
                                   mc);
  epi_kernel<<<dim3(512, 32), 256, 0, stream>>>(IOUc, F, h0, c0, idd, cidx,
                                                outh, outc);
}